// Round 1
// baseline (6342.199 us; speedup 1.0000x reference)
//
#include <hip/hip_runtime.h>

typedef unsigned short u16;
typedef unsigned int   u32;
typedef __attribute__((ext_vector_type(8))) __bf16 bfv8;
typedef __attribute__((ext_vector_type(4))) float  f32x4;

// ---------- helpers ----------
__device__ __forceinline__ u16 f2bf(float f){
  u32 u = __builtin_bit_cast(u32, f);
  return (u16)((u + 0x7FFFu + ((u >> 16) & 1u)) >> 16);   // RNE
}
__device__ __forceinline__ float bf2f(u16 b){
  return __builtin_bit_cast(float, ((u32)b) << 16);
}
__device__ __forceinline__ u32 pk2(float a, float b){
  return (u32)f2bf(a) | ((u32)f2bf(b) << 16);
}
__device__ __forceinline__ float wsum(float v){
  #pragma unroll
  for (int m = 32; m > 0; m >>= 1) v += __shfl_xor(v, m, 64);
  return v;
}

// ---------- GEMM: C[M,N] = A[M,K](bf16) * W[N,K]^T (f32 -> bf16 in staging) ----------
// EPI: 0 = f32 store, 1 = bf16 store, 2 = gate-combine (sigmoid(acc)*aux0+(1-s)*aux1 -> bf16),
//      3 = silu(aux0)*acc -> bf16, 4 = f32 residual add (Cf += acc)
template<int EPI>
__global__ __launch_bounds__(256) void flm_gemm(
    const u16* __restrict__ A, int lda,
    const float* __restrict__ Bw, int ldb,
    float* __restrict__ Cf, u16* __restrict__ Cb, int ldc,
    const float* __restrict__ aux0, const float* __restrict__ aux1,
    int K)
{
  __shared__ u16 sA[128][72];
  __shared__ u16 sB[128][72];
  const int tid  = threadIdx.x;
  const int lane = tid & 63;
  const int wave = tid >> 6;
  const int row0 = blockIdx.y * 128;
  const int col0 = blockIdx.x * 128;
  const int wr = (wave >> 1) * 64;
  const int wc = (wave & 1) * 64;

  f32x4 acc[4][4];
  #pragma unroll
  for (int m = 0; m < 4; m++)
    #pragma unroll
    for (int n = 0; n < 4; n++)
      acc[m][n] = (f32x4){0.f, 0.f, 0.f, 0.f};

  for (int k0 = 0; k0 < K; k0 += 64){
    // stage A tile [128][64] bf16 (4 passes x 16B/thread)
    #pragma unroll
    for (int i = 0; i < 4; i++){
      int idx = tid + i * 256;
      int r = idx >> 3, c = (idx & 7) * 8;
      uint4 v = *(const uint4*)(A + (size_t)(row0 + r) * lda + k0 + c);
      *(uint4*)&sA[r][c] = v;
    }
    // stage B tile [128][64] f32 -> bf16 (8 passes x 16B/thread)
    #pragma unroll
    for (int i = 0; i < 8; i++){
      int idx = tid + i * 256;
      int r = idx >> 4, c = (idx & 15) * 4;
      float4 v = *(const float4*)(Bw + (size_t)(col0 + r) * ldb + k0 + c);
      uint2 p; p.x = pk2(v.x, v.y); p.y = pk2(v.z, v.w);
      *(uint2*)&sB[r][c] = p;
    }
    __syncthreads();
    #pragma unroll
    for (int kk = 0; kk < 2; kk++){
      bfv8 af[4], bfr[4];
      #pragma unroll
      for (int m = 0; m < 4; m++)
        af[m] = *(const bfv8*)&sA[wr + m*16 + (lane & 15)][kk*32 + (lane >> 4) * 8];
      #pragma unroll
      for (int n = 0; n < 4; n++)
        bfr[n] = *(const bfv8*)&sB[wc + n*16 + (lane & 15)][kk*32 + (lane >> 4) * 8];
      #pragma unroll
      for (int m = 0; m < 4; m++)
        #pragma unroll
        for (int n = 0; n < 4; n++)
          acc[m][n] = __builtin_amdgcn_mfma_f32_16x16x32_bf16(af[m], bfr[n], acc[m][n], 0, 0, 0);
    }
    __syncthreads();
  }

  // epilogue: D row = (lane>>4)*4 + j, col = lane&15  [measured m89/m91]
  #pragma unroll
  for (int m = 0; m < 4; m++){
    int rbase = row0 + wr + m*16 + (lane >> 4) * 4;
    #pragma unroll
    for (int n = 0; n < 4; n++){
      int col = col0 + wc + n*16 + (lane & 15);
      #pragma unroll
      for (int j = 0; j < 4; j++){
        float v = acc[m][n][j];
        size_t o = (size_t)(rbase + j) * ldc + col;
        if (EPI == 0) Cf[o] = v;
        else if (EPI == 1) Cb[o] = f2bf(v);
        else if (EPI == 2){
          float sg = 1.f / (1.f + expf(-v));
          Cb[o] = f2bf(sg * aux0[o] + (1.f - sg) * aux1[o]);
        } else if (EPI == 3){
          float g = aux0[o];
          float sg = g / (1.f + expf(-g));
          Cb[o] = f2bf(sg * v);
        } else { // 4
          Cf[o] += v;
        }
      }
    }
  }
}

// ---------- embedding gather + rmsnorm -> f32 h ----------
__global__ __launch_bounds__(256) void flm_embed(
    const int* __restrict__ x, const float* __restrict__ embed,
    const float* __restrict__ w, float* __restrict__ h)
{
  int t = blockIdx.x, tid = threadIdx.x;
  int tok = x[t];
  float4 v = ((const float4*)(embed + (size_t)tok * 1024))[tid];
  float ss = v.x*v.x + v.y*v.y + v.z*v.z + v.w*v.w;
  ss = wsum(ss);
  __shared__ float red[4];
  if ((tid & 63) == 0) red[tid >> 6] = ss;
  __syncthreads();
  float inv = rsqrtf((red[0]+red[1]+red[2]+red[3]) * (1.f/1024.f) + 1e-6f);
  float4 wv = ((const float4*)w)[tid];
  float4 o; o.x = v.x*inv*wv.x; o.y = v.y*inv*wv.y; o.z = v.z*inv*wv.z; o.w = v.w*inv*wv.w;
  ((float4*)(h + (size_t)t * 1024))[tid] = o;
}

// ---------- rmsnorm: h(f32) -> up to two bf16 outputs ----------
__global__ __launch_bounds__(256) void flm_rms(
    const float* __restrict__ h, const float* __restrict__ w1, const float* __restrict__ w2,
    u16* __restrict__ o1, u16* __restrict__ o2)
{
  int t = blockIdx.x, tid = threadIdx.x;
  float4 v = ((const float4*)(h + (size_t)t * 1024))[tid];
  float ss = v.x*v.x + v.y*v.y + v.z*v.z + v.w*v.w;
  ss = wsum(ss);
  __shared__ float red[4];
  if ((tid & 63) == 0) red[tid >> 6] = ss;
  __syncthreads();
  float inv = rsqrtf((red[0]+red[1]+red[2]+red[3]) * (1.f/1024.f) + 1e-6f);
  {
    float4 wv = ((const float4*)w1)[tid];
    uint2 p; p.x = pk2(v.x*inv*wv.x, v.y*inv*wv.y); p.y = pk2(v.z*inv*wv.z, v.w*inv*wv.w);
    ((uint2*)(o1 + (size_t)t * 1024))[tid] = p;
  }
  if (o2 != nullptr){
    float4 wv = ((const float4*)w2)[tid];
    uint2 p; p.x = pk2(v.x*inv*wv.x, v.y*inv*wv.y); p.y = pk2(v.z*inv*wv.z, v.w*inv*wv.w);
    ((uint2*)(o2 + (size_t)t * 1024))[tid] = p;
  }
}

// ---------- beta = sigmoid(h2 @ beta_w^T), [T][16] ----------
__global__ __launch_bounds__(64) void flm_beta(
    const u16* __restrict__ h2, const float* __restrict__ bw, float* __restrict__ beta)
{
  int t = blockIdx.x, lane = threadIdx.x;
  float hv[16];
  #pragma unroll
  for (int i = 0; i < 16; i++) hv[i] = bf2f(h2[(size_t)t*1024 + i*64 + lane]);
  for (int h = 0; h < 16; h++){
    float p = 0.f;
    #pragma unroll
    for (int i = 0; i < 16; i++) p += hv[i] * bw[h*1024 + i*64 + lane];
    p = wsum(p);
    if (lane == 0) beta[t*16 + h] = 1.f / (1.f + expf(-p));
  }
}

// ---------- normalize keys & queries per (t,h) over DM=64 ----------
__global__ __launch_bounds__(64) void flm_normkq(u16* __restrict__ keys, u16* __restrict__ queries)
{
  int t = blockIdx.x, h = blockIdx.y;
  u16* arr = blockIdx.z ? queries : keys;
  size_t idx = (size_t)t * 1024 + h * 64 + threadIdx.x;
  float v = bf2f(arr[idx]);
  float ss = wsum(v * v);
  float nrm = fmaxf(sqrtf(ss), 1e-12f);
  arr[idx] = f2bf(v / nrm);
}

// ---------- sliding-window attention, one wave per (q,h) ----------
__global__ __launch_bounds__(64) void flm_swa(const u16* __restrict__ qkv, u16* __restrict__ out)
{
  int q = blockIdx.x, h = blockIdx.y, lane = threadIdx.x;
  int base = h * 64;
  float qv = bf2f(qkv[(size_t)q * 3072 + base + lane]);
  int klo = q - 255; if (klo < 0) klo = 0;
  int n = q - klo + 1;                       // 1..256 allowed keys
  float s[4];
  float mx = -1e30f;
  #pragma unroll
  for (int c = 0; c < 4; c++){
    s[c] = -1e30f;
    int b0 = c * 64;
    if (b0 < n){
      int m = n - b0; if (m > 64) m = 64;
      for (int kin = 0; kin < m; kin++){
        int k = klo + b0 + kin;
        float p = qv * bf2f(qkv[(size_t)k * 3072 + 1024 + base + lane]);
        p = wsum(p) * 0.125f;
        if (kin == lane) s[c] = p;
        mx = fmaxf(mx, p);
      }
    }
  }
  float denom = 0.f;
  #pragma unroll
  for (int c = 0; c < 4; c++){
    float e = (c * 64 + lane < n) ? expf(s[c] - mx) : 0.f;
    s[c] = e;
    denom += e;
  }
  denom = wsum(denom);
  float invd = 1.f / denom;
  float o = 0.f;
  #pragma unroll
  for (int c = 0; c < 4; c++){
    int b0 = c * 64;
    if (b0 < n){
      int m = n - b0; if (m > 64) m = 64;
      for (int kin = 0; kin < m; kin++){
        float p = __shfl(s[c], kin, 64);
        o += p * bf2f(qkv[(size_t)(klo + b0 + kin) * 3072 + 2048 + base + lane]);
      }
    }
  }
  out[(size_t)q * 1024 + base + lane] = f2bf(o * invd);
}

// ---------- delta rule: out_i = sum_{j>=i} (q_i.k_j)/8 * v_j + beta_i * v_i ----------
__global__ __launch_bounds__(64) void flm_delta(
    const u16* __restrict__ keys, const u16* __restrict__ values, const u16* __restrict__ queries,
    const float* __restrict__ beta, u16* __restrict__ out)
{
  int i = blockIdx.x, h = blockIdx.y, lane = threadIdx.x;
  int base = h * 64;
  float qv = bf2f(queries[(size_t)i * 1024 + base + lane]);
  float o = beta[i*16 + h] * bf2f(values[(size_t)i * 1024 + base + lane]);
  for (int j = i; j < 1024; j++){
    float p = qv * bf2f(keys[(size_t)j * 1024 + base + lane]);
    p = wsum(p);
    o += p * 0.125f * bf2f(values[(size_t)j * 1024 + base + lane]);
  }
  out[(size_t)i * 1024 + base + lane] = f2bf(o);
}

// ---------- launch ----------
extern "C" void kernel_launch(void* const* d_in, const int* in_sizes, int n_in,
                              void* d_out, int out_size, void* d_ws, size_t ws_size,
                              hipStream_t stream)
{
  (void)in_sizes; (void)n_in; (void)out_size; (void)ws_size;
  const int*   x        = (const int*)d_in[0];
  const float* embed    = (const float*)d_in[1];
  const float* ln_in_w  = (const float*)d_in[2];
  const float* ln1_w    = (const float*)d_in[3];
  const float* lnd_w    = (const float*)d_in[4];
  const float* qkv_w    = (const float*)d_in[5];
  const float* swa_out_w= (const float*)d_in[6];
  const float* k_w      = (const float*)d_in[7];
  const float* v_w      = (const float*)d_in[8];
  const float* q_w      = (const float*)d_in[9];
  const float* beta_w   = (const float*)d_in[10];
  const float* mem_out_w= (const float*)d_in[11];
  const float* gate_w   = (const float*)d_in[12];
  const float* comb_w   = (const float*)d_in[13];
  const float* ln2_w    = (const float*)d_in[14];
  const float* wg       = (const float*)d_in[15];
  const float* wu       = (const float*)d_in[16];
  const float* wo       = (const float*)d_in[17];
  const float* ln_out_w = (const float*)d_in[18];
  float* out = (float*)d_out;

  char* ws = (char*)d_ws;
  const size_t MB = 1u << 20;
  float* h       = (float*)(ws + 0);                 // 4 MB
  u16*   h1      = (u16*)  (ws + 4*MB);              // 2 MB
  u16*   h2      = (u16*)  (ws + 6*MB);              // 2 MB
  u16*   qkvb    = (u16*)  (ws + 8*MB);              // 6 MB
  u16*   keys    = (u16*)  (ws + 14*MB);             // 2 MB
  u16*   values  = (u16*)  (ws + 16*MB);             // 2 MB
  u16*   queries = (u16*)  (ws + 18*MB);             // 2 MB
  float* beta    = (float*)(ws + 20*MB);             // 64 KB
  u16*   attn    = (u16*)  (ws + 20*MB + 256*1024);  // 2 MB
  u16*   delt    = (u16*)  (ws + 22*MB + 256*1024);  // 2 MB
  float* localb  = (float*)(ws + 24*MB + 256*1024);  // 4 MB
  float* globb   = (float*)(ws + 28*MB + 256*1024);  // 4 MB
  u16*   mcomb   = (u16*)  (ws + 32*MB + 256*1024);  // 2 MB
  u16*   hn      = (u16*)  (ws + 34*MB + 256*1024);  // 2 MB
  float* g       = (float*)(ws + 8*MB);              // 16 MB, aliases qkv/kvq (dead by FFN)
  u16*   sbuf    = (u16*)  (ws + 36*MB + 256*1024);  // 8 MB  -> total 44.25 MB

  flm_embed<<<1024, 256, 0, stream>>>(x, embed, ln_in_w, h);

  for (int l = 0; l < 4; l++){
    flm_rms<<<1024, 256, 0, stream>>>(h, ln1_w + l*1024, lnd_w + l*1024, h1, h2);
    flm_gemm<1><<<dim3(24, 8), 256, 0, stream>>>(h1, 1024, qkv_w + (size_t)l*3072*1024, 1024,
                                                 nullptr, qkvb, 3072, nullptr, nullptr, 1024);
    flm_gemm<1><<<dim3(8, 8), 256, 0, stream>>>(h2, 1024, k_w + (size_t)l*1024*1024, 1024,
                                                nullptr, keys, 1024, nullptr, nullptr, 1024);
    flm_gemm<1><<<dim3(8, 8), 256, 0, stream>>>(h2, 1024, v_w + (size_t)l*1024*1024, 1024,
                                                nullptr, values, 1024, nullptr, nullptr, 1024);
    flm_gemm<1><<<dim3(8, 8), 256, 0, stream>>>(h2, 1024, q_w + (size_t)l*1024*1024, 1024,
                                                nullptr, queries, 1024, nullptr, nullptr, 1024);
    flm_beta<<<1024, 64, 0, stream>>>(h2, beta_w + (size_t)l*16*1024, beta);
    flm_normkq<<<dim3(1024, 16, 2), 64, 0, stream>>>(keys, queries);
    flm_swa<<<dim3(1024, 16), 64, 0, stream>>>(qkvb, attn);
    flm_delta<<<dim3(1024, 16), 64, 0, stream>>>(keys, values, queries, beta, delt);
    flm_gemm<0><<<dim3(8, 8), 256, 0, stream>>>(attn, 1024, swa_out_w + (size_t)l*1024*1024, 1024,
                                                localb, nullptr, 1024, nullptr, nullptr, 1024);
    flm_gemm<0><<<dim3(8, 8), 256, 0, stream>>>(delt, 1024, mem_out_w + (size_t)l*1024*1024, 1024,
                                                globb, nullptr, 1024, nullptr, nullptr, 1024);
    flm_gemm<2><<<dim3(8, 8), 256, 0, stream>>>(h1, 1024, gate_w + (size_t)l*1024*1024, 1024,
                                                nullptr, mcomb, 1024, localb, globb, 1024);
    flm_gemm<4><<<dim3(8, 8), 256, 0, stream>>>(mcomb, 1024, comb_w + (size_t)l*1024*1024, 1024,
                                                h, nullptr, 1024, nullptr, nullptr, 1024);
    flm_rms<<<1024, 256, 0, stream>>>(h, ln2_w + l*1024, nullptr, hn, nullptr);
    flm_gemm<0><<<dim3(32, 8), 256, 0, stream>>>(hn, 1024, wg + (size_t)l*4096*1024, 1024,
                                                 g, nullptr, 4096, nullptr, nullptr, 1024);
    flm_gemm<3><<<dim3(32, 8), 256, 0, stream>>>(hn, 1024, wu + (size_t)l*4096*1024, 1024,
                                                 nullptr, sbuf, 4096, g, nullptr, 1024);
    flm_gemm<4><<<dim3(8, 8), 256, 0, stream>>>(sbuf, 4096, wo + (size_t)l*1024*4096, 4096,
                                                h, nullptr, 1024, nullptr, nullptr, 4096);
  }

  flm_rms<<<1024, 256, 0, stream>>>(h, ln_out_w, nullptr, hn, nullptr);
  flm_gemm<0><<<dim3(250, 8), 256, 0, stream>>>(hn, 1024, embed, 1024,
                                                out, nullptr, 32000, nullptr, nullptr, 1024);
}

// Round 2
// 2288.716 us; speedup vs baseline: 2.7711x; 2.7711x over previous
//
#include <hip/hip_runtime.h>

typedef unsigned short u16;
typedef unsigned int   u32;
typedef __attribute__((ext_vector_type(8))) __bf16 bfv8;
typedef __attribute__((ext_vector_type(4))) float  f32x4;

// ---------- helpers ----------
__device__ __forceinline__ u16 f2bf(float f){
  u32 u = __builtin_bit_cast(u32, f);
  return (u16)((u + 0x7FFFu + ((u >> 16) & 1u)) >> 16);   // RNE
}
__device__ __forceinline__ float bf2f(u16 b){
  return __builtin_bit_cast(float, ((u32)b) << 16);
}
__device__ __forceinline__ u32 pk2(float a, float b){
  return (u32)f2bf(a) | ((u32)f2bf(b) << 16);
}
__device__ __forceinline__ float wsum(float v){
  #pragma unroll
  for (int m = 32; m > 0; m >>= 1) v += __shfl_xor(v, m, 64);
  return v;
}

// ---------- GEMM: C[M,N] = A[M,K](bf16) * W[N,K]^T (f32 -> bf16 in staging) ----------
// EPI: 0 = f32 store, 1 = bf16 store, 2 = gate-combine (sigmoid(acc)*aux0+(1-s)*aux1 -> bf16),
//      3 = silu(aux0)*acc -> bf16, 4 = f32 residual add (Cf += acc)
template<int EPI>
__global__ __launch_bounds__(256) void flm_gemm(
    const u16* __restrict__ A, int lda,
    const float* __restrict__ Bw, int ldb,
    float* __restrict__ Cf, u16* __restrict__ Cb, int ldc,
    const float* __restrict__ aux0, const float* __restrict__ aux1,
    int K)
{
  __shared__ u16 sA[128][72];
  __shared__ u16 sB[128][72];
  const int tid  = threadIdx.x;
  const int lane = tid & 63;
  const int wave = tid >> 6;
  const int row0 = blockIdx.y * 128;
  const int col0 = blockIdx.x * 128;
  const int wr = (wave >> 1) * 64;
  const int wc = (wave & 1) * 64;

  f32x4 acc[4][4];
  #pragma unroll
  for (int m = 0; m < 4; m++)
    #pragma unroll
    for (int n = 0; n < 4; n++)
      acc[m][n] = (f32x4){0.f, 0.f, 0.f, 0.f};

  for (int k0 = 0; k0 < K; k0 += 64){
    #pragma unroll
    for (int i = 0; i < 4; i++){
      int idx = tid + i * 256;
      int r = idx >> 3, c = (idx & 7) * 8;
      uint4 v = *(const uint4*)(A + (size_t)(row0 + r) * lda + k0 + c);
      *(uint4*)&sA[r][c] = v;
    }
    #pragma unroll
    for (int i = 0; i < 8; i++){
      int idx = tid + i * 256;
      int r = idx >> 4, c = (idx & 15) * 4;
      float4 v = *(const float4*)(Bw + (size_t)(col0 + r) * ldb + k0 + c);
      uint2 p; p.x = pk2(v.x, v.y); p.y = pk2(v.z, v.w);
      *(uint2*)&sB[r][c] = p;
    }
    __syncthreads();
    #pragma unroll
    for (int kk = 0; kk < 2; kk++){
      bfv8 af[4], bfr[4];
      #pragma unroll
      for (int m = 0; m < 4; m++)
        af[m] = *(const bfv8*)&sA[wr + m*16 + (lane & 15)][kk*32 + (lane >> 4) * 8];
      #pragma unroll
      for (int n = 0; n < 4; n++)
        bfr[n] = *(const bfv8*)&sB[wc + n*16 + (lane & 15)][kk*32 + (lane >> 4) * 8];
      #pragma unroll
      for (int m = 0; m < 4; m++)
        #pragma unroll
        for (int n = 0; n < 4; n++)
          acc[m][n] = __builtin_amdgcn_mfma_f32_16x16x32_bf16(af[m], bfr[n], acc[m][n], 0, 0, 0);
    }
    __syncthreads();
  }

  #pragma unroll
  for (int m = 0; m < 4; m++){
    int rbase = row0 + wr + m*16 + (lane >> 4) * 4;
    #pragma unroll
    for (int n = 0; n < 4; n++){
      int col = col0 + wc + n*16 + (lane & 15);
      #pragma unroll
      for (int j = 0; j < 4; j++){
        float v = acc[m][n][j];
        size_t o = (size_t)(rbase + j) * ldc + col;
        if (EPI == 0) Cf[o] = v;
        else if (EPI == 1) Cb[o] = f2bf(v);
        else if (EPI == 2){
          float sg = 1.f / (1.f + expf(-v));
          Cb[o] = f2bf(sg * aux0[o] + (1.f - sg) * aux1[o]);
        } else if (EPI == 3){
          float g = aux0[o];
          float sg = g / (1.f + expf(-g));
          Cb[o] = f2bf(sg * v);
        } else {
          Cf[o] += v;
        }
      }
    }
  }
}

// ---------- embedding gather + rmsnorm -> f32 h ----------
__global__ __launch_bounds__(256) void flm_embed(
    const int* __restrict__ x, const float* __restrict__ embed,
    const float* __restrict__ w, float* __restrict__ h)
{
  int t = blockIdx.x, tid = threadIdx.x;
  int tok = x[t];
  float4 v = ((const float4*)(embed + (size_t)tok * 1024))[tid];
  float ss = v.x*v.x + v.y*v.y + v.z*v.z + v.w*v.w;
  ss = wsum(ss);
  __shared__ float red[4];
  if ((tid & 63) == 0) red[tid >> 6] = ss;
  __syncthreads();
  float inv = rsqrtf((red[0]+red[1]+red[2]+red[3]) * (1.f/1024.f) + 1e-6f);
  float4 wv = ((const float4*)w)[tid];
  float4 o; o.x = v.x*inv*wv.x; o.y = v.y*inv*wv.y; o.z = v.z*inv*wv.z; o.w = v.w*inv*wv.w;
  ((float4*)(h + (size_t)t * 1024))[tid] = o;
}

// ---------- rmsnorm: h(f32) -> up to two bf16 outputs ----------
__global__ __launch_bounds__(256) void flm_rms(
    const float* __restrict__ h, const float* __restrict__ w1, const float* __restrict__ w2,
    u16* __restrict__ o1, u16* __restrict__ o2)
{
  int t = blockIdx.x, tid = threadIdx.x;
  float4 v = ((const float4*)(h + (size_t)t * 1024))[tid];
  float ss = v.x*v.x + v.y*v.y + v.z*v.z + v.w*v.w;
  ss = wsum(ss);
  __shared__ float red[4];
  if ((tid & 63) == 0) red[tid >> 6] = ss;
  __syncthreads();
  float inv = rsqrtf((red[0]+red[1]+red[2]+red[3]) * (1.f/1024.f) + 1e-6f);
  {
    float4 wv = ((const float4*)w1)[tid];
    uint2 p; p.x = pk2(v.x*inv*wv.x, v.y*inv*wv.y); p.y = pk2(v.z*inv*wv.z, v.w*inv*wv.w);
    ((uint2*)(o1 + (size_t)t * 1024))[tid] = p;
  }
  if (o2 != nullptr){
    float4 wv = ((const float4*)w2)[tid];
    uint2 p; p.x = pk2(v.x*inv*wv.x, v.y*inv*wv.y); p.y = pk2(v.z*inv*wv.z, v.w*inv*wv.w);
    ((uint2*)(o2 + (size_t)t * 1024))[tid] = p;
  }
}

// ---------- beta = sigmoid(h2 @ beta_w^T), [T][16] ----------
__global__ __launch_bounds__(64) void flm_beta(
    const u16* __restrict__ h2, const float* __restrict__ bw, float* __restrict__ beta)
{
  int t = blockIdx.x, lane = threadIdx.x;
  float hv[16];
  #pragma unroll
  for (int i = 0; i < 16; i++) hv[i] = bf2f(h2[(size_t)t*1024 + i*64 + lane]);
  for (int h = 0; h < 16; h++){
    float p = 0.f;
    #pragma unroll
    for (int i = 0; i < 16; i++) p += hv[i] * bw[h*1024 + i*64 + lane];
    p = wsum(p);
    if (lane == 0) beta[t*16 + h] = 1.f / (1.f + expf(-p));
  }
}

// ---------- normalize keys & queries per (t,h) over DM=64 ----------
__global__ __launch_bounds__(64) void flm_normkq(u16* __restrict__ keys, u16* __restrict__ queries)
{
  int t = blockIdx.x, h = blockIdx.y;
  u16* arr = blockIdx.z ? queries : keys;
  size_t idx = (size_t)t * 1024 + h * 64 + threadIdx.x;
  float v = bf2f(arr[idx]);
  float ss = wsum(v * v);
  float nrm = fmaxf(sqrtf(ss), 1e-12f);
  arr[idx] = f2bf(v / nrm);
}

// ---------- MFMA sliding-window attention ----------
// block: (qt, h); 4 waves, each owns 16 q-rows of the 64-row tile.
// online softmax over <=5 key tiles, diagonal first (running max always finite).
__global__ __launch_bounds__(256) void flm_swa_mfma(const u16* __restrict__ qkv, u16* __restrict__ out)
{
  __shared__ u16 sK[64][72];
  __shared__ u16 sVt[64][72];
  __shared__ u16 sP[4][16][72];
  const int tid = threadIdx.x, lane = tid & 63, w = tid >> 6;
  const int qt = blockIdx.x, h = blockIdx.y;
  const int base = h * 64;

  bfv8 aq[2];
  {
    int qrow = qt*64 + w*16 + (lane & 15);
    #pragma unroll
    for (int kk = 0; kk < 2; kk++)
      aq[kk] = *(const bfv8*)(qkv + (size_t)qrow*3072 + base + kk*32 + (lane>>4)*8);
  }

  f32x4 acc_o[4];
  float m_r[4], l_r[4];
  #pragma unroll
  for (int n = 0; n < 4; n++) acc_o[n] = (f32x4){0.f,0.f,0.f,0.f};
  #pragma unroll
  for (int r = 0; r < 4; r++){ m_r[r] = -1e30f; l_r[r] = 0.f; }

  const int jt0 = (qt >= 4) ? qt - 4 : 0;
  const int ri = w*16 + (lane>>4)*4;           // tile-local row base for this lane

  for (int jt = qt; jt >= jt0; jt--){
    // stage K tile [64][64] and V^T tile
    #pragma unroll
    for (int i = 0; i < 2; i++){
      int idx = tid + i*256;
      int r = idx >> 3, c = (idx & 7) * 8;
      uint4 kv = *(const uint4*)(qkv + (size_t)(jt*64+r)*3072 + 1024 + base + c);
      *(uint4*)&sK[r][c] = kv;
      uint4 vv = *(const uint4*)(qkv + (size_t)(jt*64+r)*3072 + 2048 + base + c);
      u16 tmp[8]; *(uint4*)tmp = vv;
      #pragma unroll
      for (int e = 0; e < 8; e++) sVt[c+e][r] = tmp[e];
    }
    __syncthreads();

    // S = Q K^T * 0.125 (per wave: 16 x 64)
    f32x4 sv[4];
    #pragma unroll
    for (int n = 0; n < 4; n++) sv[n] = (f32x4){0.f,0.f,0.f,0.f};
    #pragma unroll
    for (int kk = 0; kk < 2; kk++){
      #pragma unroll
      for (int n = 0; n < 4; n++){
        bfv8 bk = *(const bfv8*)&sK[n*16 + (lane & 15)][(lane>>4)*8 + kk*32];
        sv[n] = __builtin_amdgcn_mfma_f32_16x16x32_bf16(aq[kk], bk, sv[n], 0, 0, 0);
      }
    }
    // scale + mask
    #pragma unroll
    for (int n = 0; n < 4; n++){
      int cj = n*16 + (lane & 15);
      #pragma unroll
      for (int r = 0; r < 4; r++){
        float s = sv[n][r] * 0.125f;
        if (jt == qt)      { if (cj > ri + r) s = -1e30f; }   // causal: j <= i
        else if (jt == jt0 && qt - jt0 == 4) { if (cj <= ri + r) s = -1e30f; } // dist < 256
        sv[n][r] = s;
      }
    }
    // online softmax per row
    float pv[4][4], scl[4];
    #pragma unroll
    for (int r = 0; r < 4; r++){
      float mx = -1e30f;
      #pragma unroll
      for (int n = 0; n < 4; n++) mx = fmaxf(mx, sv[n][r]);
      #pragma unroll
      for (int m = 1; m < 16; m <<= 1) mx = fmaxf(mx, __shfl_xor(mx, m, 64));
      float mn = fmaxf(m_r[r], mx);
      float sc = expf(m_r[r] - mn);
      m_r[r] = mn; scl[r] = sc;
      float rs = 0.f;
      #pragma unroll
      for (int n = 0; n < 4; n++){ float p = expf(sv[n][r] - mn); pv[n][r] = p; rs += p; }
      #pragma unroll
      for (int m = 1; m < 16; m <<= 1) rs += __shfl_xor(rs, m, 64);
      l_r[r] = l_r[r] * sc + rs;
    }
    // rescale O, write P to LDS (bf16)
    #pragma unroll
    for (int n = 0; n < 4; n++){
      #pragma unroll
      for (int r = 0; r < 4; r++){
        acc_o[n][r] *= scl[r];
        sP[w][(lane>>4)*4 + r][n*16 + (lane & 15)] = f2bf(pv[n][r]);
      }
    }
    // O += P V
    #pragma unroll
    for (int kk = 0; kk < 2; kk++){
      bfv8 ap = *(const bfv8*)&sP[w][lane & 15][(lane>>4)*8 + kk*32];
      #pragma unroll
      for (int n = 0; n < 4; n++){
        bfv8 bv = *(const bfv8*)&sVt[n*16 + (lane & 15)][(lane>>4)*8 + kk*32];
        acc_o[n] = __builtin_amdgcn_mfma_f32_16x16x32_bf16(ap, bv, acc_o[n], 0, 0, 0);
      }
    }
    __syncthreads();
  }

  #pragma unroll
  for (int n = 0; n < 4; n++){
    int col = base + n*16 + (lane & 15);
    #pragma unroll
    for (int r = 0; r < 4; r++){
      int row = qt*64 + ri + r;
      out[(size_t)row*1024 + col] = f2bf(acc_o[n][r] / l_r[r]);
    }
  }
}

// ---------- MFMA delta rule: out_i = sum_{j>=i} (q.k)/8 v_j + beta_i v_i ----------
__global__ __launch_bounds__(256) void flm_delta_mfma(
    const u16* __restrict__ keys, const u16* __restrict__ values, const u16* __restrict__ queries,
    const float* __restrict__ beta, u16* __restrict__ out)
{
  __shared__ u16 sK[64][72];
  __shared__ u16 sVt[64][72];
  __shared__ u16 sP[4][16][72];
  const int tid = threadIdx.x, lane = tid & 63, w = tid >> 6;
  const int qt = blockIdx.x, h = blockIdx.y;
  const int base = h * 64;

  bfv8 aq[2];
  {
    int qrow = qt*64 + w*16 + (lane & 15);
    #pragma unroll
    for (int kk = 0; kk < 2; kk++)
      aq[kk] = *(const bfv8*)(queries + (size_t)qrow*1024 + base + kk*32 + (lane>>4)*8);
  }

  f32x4 acc_o[4];
  #pragma unroll
  for (int n = 0; n < 4; n++) acc_o[n] = (f32x4){0.f,0.f,0.f,0.f};
  const int ri = w*16 + (lane>>4)*4;

  for (int jt = qt; jt < 16; jt++){
    #pragma unroll
    for (int i = 0; i < 2; i++){
      int idx = tid + i*256;
      int r = idx >> 3, c = (idx & 7) * 8;
      uint4 kv = *(const uint4*)(keys + (size_t)(jt*64+r)*1024 + base + c);
      *(uint4*)&sK[r][c] = kv;
      uint4 vv = *(const uint4*)(values + (size_t)(jt*64+r)*1024 + base + c);
      u16 tmp[8]; *(uint4*)tmp = vv;
      #pragma unroll
      for (int e = 0; e < 8; e++) sVt[c+e][r] = tmp[e];
    }
    __syncthreads();

    f32x4 sv[4];
    #pragma unroll
    for (int n = 0; n < 4; n++) sv[n] = (f32x4){0.f,0.f,0.f,0.f};
    #pragma unroll
    for (int kk = 0; kk < 2; kk++){
      #pragma unroll
      for (int n = 0; n < 4; n++){
        bfv8 bk = *(const bfv8*)&sK[n*16 + (lane & 15)][(lane>>4)*8 + kk*32];
        sv[n] = __builtin_amdgcn_mfma_f32_16x16x32_bf16(aq[kk], bk, sv[n], 0, 0, 0);
      }
    }
    // P = S/8 masked to j >= i (only diagonal tile partial)
    #pragma unroll
    for (int n = 0; n < 4; n++){
      int cj = n*16 + (lane & 15);
      #pragma unroll
      for (int r = 0; r < 4; r++){
        float p = sv[n][r] * 0.125f;
        if (jt == qt && cj < ri + r) p = 0.f;
        sP[w][(lane>>4)*4 + r][n*16 + (lane & 15)] = f2bf(p);
      }
    }
    #pragma unroll
    for (int kk = 0; kk < 2; kk++){
      bfv8 ap = *(const bfv8*)&sP[w][lane & 15][(lane>>4)*8 + kk*32];
      #pragma unroll
      for (int n = 0; n < 4; n++){
        bfv8 bv = *(const bfv8*)&sVt[n*16 + (lane & 15)][(lane>>4)*8 + kk*32];
        acc_o[n] = __builtin_amdgcn_mfma_f32_16x16x32_bf16(ap, bv, acc_o[n], 0, 0, 0);
      }
    }
    __syncthreads();
  }

  #pragma unroll
  for (int n = 0; n < 4; n++){
    int col = base + n*16 + (lane & 15);
    #pragma unroll
    for (int r = 0; r < 4; r++){
      int row = qt*64 + ri + r;
      float b = beta[row*16 + h];
      float v = bf2f(values[(size_t)row*1024 + col]);
      out[(size_t)row*1024 + col] = f2bf(acc_o[n][r] + b * v);
    }
  }
}

// ---------- launch ----------
extern "C" void kernel_launch(void* const* d_in, const int* in_sizes, int n_in,
                              void* d_out, int out_size, void* d_ws, size_t ws_size,
                              hipStream_t stream)
{
  (void)in_sizes; (void)n_in; (void)out_size; (void)ws_size;
  const int*   x        = (const int*)d_in[0];
  const float* embed    = (const float*)d_in[1];
  const float* ln_in_w  = (const float*)d_in[2];
  const float* ln1_w    = (const float*)d_in[3];
  const float* lnd_w    = (const float*)d_in[4];
  const float* qkv_w    = (const float*)d_in[5];
  const float* swa_out_w= (const float*)d_in[6];
  const float* k_w      = (const float*)d_in[7];
  const float* v_w      = (const float*)d_in[8];
  const float* q_w      = (const float*)d_in[9];
  const float* beta_w   = (const float*)d_in[10];
  const float* mem_out_w= (const float*)d_in[11];
  const float* gate_w   = (const float*)d_in[12];
  const float* comb_w   = (const float*)d_in[13];
  const float* ln2_w    = (const float*)d_in[14];
  const float* wg       = (const float*)d_in[15];
  const float* wu       = (const float*)d_in[16];
  const float* wo       = (const float*)d_in[17];
  const float* ln_out_w = (const float*)d_in[18];
  float* out = (float*)d_out;

  char* ws = (char*)d_ws;
  const size_t MB = 1u << 20;
  float* h       = (float*)(ws + 0);
  u16*   h1      = (u16*)  (ws + 4*MB);
  u16*   h2      = (u16*)  (ws + 6*MB);
  u16*   qkvb    = (u16*)  (ws + 8*MB);
  u16*   keys    = (u16*)  (ws + 14*MB);
  u16*   values  = (u16*)  (ws + 16*MB);
  u16*   queries = (u16*)  (ws + 18*MB);
  float* beta    = (float*)(ws + 20*MB);
  u16*   attn    = (u16*)  (ws + 20*MB + 256*1024);
  u16*   delt    = (u16*)  (ws + 22*MB + 256*1024);
  float* localb  = (float*)(ws + 24*MB + 256*1024);
  float* globb   = (float*)(ws + 28*MB + 256*1024);
  u16*   mcomb   = (u16*)  (ws + 32*MB + 256*1024);
  u16*   hn      = (u16*)  (ws + 34*MB + 256*1024);
  float* g       = (float*)(ws + 8*MB);
  u16*   sbuf    = (u16*)  (ws + 36*MB + 256*1024);

  flm_embed<<<1024, 256, 0, stream>>>(x, embed, ln_in_w, h);

  for (int l = 0; l < 4; l++){
    flm_rms<<<1024, 256, 0, stream>>>(h, ln1_w + l*1024, lnd_w + l*1024, h1, h2);
    flm_gemm<1><<<dim3(24, 8), 256, 0, stream>>>(h1, 1024, qkv_w + (size_t)l*3072*1024, 1024,
                                                 nullptr, qkvb, 3072, nullptr, nullptr, 1024);
    flm_gemm<1><<<dim3(8, 8), 256, 0, stream>>>(h2, 1024, k_w + (size_t)l*1024*1024, 1024,
                                                nullptr, keys, 1024, nullptr, nullptr, 1024);
    flm_gemm<1><<<dim3(8, 8), 256, 0, stream>>>(h2, 1024, v_w + (size_t)l*1024*1024, 1024,
                                                nullptr, values, 1024, nullptr, nullptr, 1024);
    flm_gemm<1><<<dim3(8, 8), 256, 0, stream>>>(h2, 1024, q_w + (size_t)l*1024*1024, 1024,
                                                nullptr, queries, 1024, nullptr, nullptr, 1024);
    flm_beta<<<1024, 64, 0, stream>>>(h2, beta_w + (size_t)l*16*1024, beta);
    flm_normkq<<<dim3(1024, 16, 2), 64, 0, stream>>>(keys, queries);
    flm_swa_mfma<<<dim3(16, 16), 256, 0, stream>>>(qkvb, attn);
    flm_delta_mfma<<<dim3(16, 16), 256, 0, stream>>>(keys, values, queries, beta, delt);
    flm_gemm<0><<<dim3(8, 8), 256, 0, stream>>>(attn, 1024, swa_out_w + (size_t)l*1024*1024, 1024,
                                                localb, nullptr, 1024, nullptr, nullptr, 1024);
    flm_gemm<0><<<dim3(8, 8), 256, 0, stream>>>(delt, 1024, mem_out_w + (size_t)l*1024*1024, 1024,
                                                globb, nullptr, 1024, nullptr, nullptr, 1024);
    flm_gemm<2><<<dim3(8, 8), 256, 0, stream>>>(h1, 1024, gate_w + (size_t)l*1024*1024, 1024,
                                                nullptr, mcomb, 1024, localb, globb, 1024);
    flm_gemm<4><<<dim3(8, 8), 256, 0, stream>>>(mcomb, 1024, comb_w + (size_t)l*1024*1024, 1024,
                                                h, nullptr, 1024, nullptr, nullptr, 1024);
    flm_rms<<<1024, 256, 0, stream>>>(h, ln2_w + l*1024, nullptr, hn, nullptr);
    flm_gemm<0><<<dim3(32, 8), 256, 0, stream>>>(hn, 1024, wg + (size_t)l*4096*1024, 1024,
                                                 g, nullptr, 4096, nullptr, nullptr, 1024);
    flm_gemm<3><<<dim3(32, 8), 256, 0, stream>>>(hn, 1024, wu + (size_t)l*4096*1024, 1024,
                                                 nullptr, sbuf, 4096, g, nullptr, 1024);
    flm_gemm<4><<<dim3(8, 8), 256, 0, stream>>>(sbuf, 4096, wo + (size_t)l*1024*4096, 4096,
                                                h, nullptr, 1024, nullptr, nullptr, 4096);
  }

  flm_rms<<<1024, 256, 0, stream>>>(h, ln_out_w, nullptr, hn, nullptr);
  flm_gemm<0><<<dim3(250, 8), 256, 0, stream>>>(hn, 1024, embed, 1024,
                                                out, nullptr, 32000, nullptr, nullptr, 1024);
}

// Round 3
// 1283.084 us; speedup vs baseline: 4.9429x; 1.7838x over previous
//
#include <hip/hip_runtime.h>

typedef unsigned short u16;
typedef unsigned int   u32;
typedef __attribute__((ext_vector_type(8))) __bf16 bfv8;
typedef __attribute__((ext_vector_type(4))) float  f32x4;

// ---------- helpers ----------
__device__ __forceinline__ u16 f2bf(float f){
  u32 u = __builtin_bit_cast(u32, f);
  return (u16)((u + 0x7FFFu + ((u >> 16) & 1u)) >> 16);   // RNE
}
__device__ __forceinline__ float bf2f(u16 b){
  return __builtin_bit_cast(float, ((u32)b) << 16);
}
__device__ __forceinline__ u32 pk2(float a, float b){
  return (u32)f2bf(a) | ((u32)f2bf(b) << 16);
}
__device__ __forceinline__ float wsum(float v){
  #pragma unroll
  for (int m = 32; m > 0; m >>= 1) v += __shfl_xor(v, m, 64);
  return v;
}

// ---------- multi-GEMM ----------
// C[M=1024? rows][cols] = A[*,K](bf16) * W[col,K]^T (f32->bf16 staged).
// Up to 4 sub-GEMMs per dispatch. All have M=1024 (nRow=8 tiles of 128).
// Block mapping: bijective XCD chunking (m204), col-major within chunk so
// consecutive blocks on one XCD share the same B column-tile (L2 reuse).
// epi: 0 = f32 store, 1 = bf16 store, 2 = gate-combine, 4 = f32 +=, 5 = f32 atomicAdd
struct GDesc {
  const u16* A; const float* Bw; float* Cf; u16* Cb;
  const float* aux0; const float* aux1;
  int lda, ldb, ldc, kbeg, kend, blk0, epi, pad;
};
struct GBatch { GDesc d[4]; int ng, total; };

__global__ __launch_bounds__(512) void flm_mgemm(GBatch gb)
{
  __shared__ u16 sA[128][72];
  __shared__ u16 sB[128][72];
  const int tid = threadIdx.x, lane = tid & 63, w = tid >> 6;

  const int T = gb.total, bid = blockIdx.x;
  const int q8 = T >> 3, r8 = T & 7, xc = bid & 7, of = bid >> 3;
  const int lin = (xc < r8 ? xc * (q8 + 1) : r8 * (q8 + 1) + (xc - r8) * q8) + of;
  int di = 0;
  #pragma unroll
  for (int i = 1; i < 4; i++) if (i < gb.ng && lin >= gb.d[i].blk0) di = i;
  const GDesc g = gb.d[di];
  const int local = lin - g.blk0;
  const int row0 = (local & 7) * 128;
  const int col0 = (local >> 3) * 128;
  const int wr = (w >> 2) * 64, wc = (w & 3) * 32;

  f32x4 acc[4][2];
  #pragma unroll
  for (int m = 0; m < 4; m++)
    #pragma unroll
    for (int n = 0; n < 2; n++)
      acc[m][n] = (f32x4){0.f, 0.f, 0.f, 0.f};

  for (int k0 = g.kbeg; k0 < g.kend; k0 += 64){
    #pragma unroll
    for (int i = 0; i < 2; i++){
      int idx = tid + i * 512;
      int r = idx >> 3, c = (idx & 7) * 8;
      *(uint4*)&sA[r][c] = *(const uint4*)(g.A + (size_t)(row0 + r) * g.lda + k0 + c);
    }
    #pragma unroll
    for (int i = 0; i < 4; i++){
      int idx = tid + i * 512;
      int r = idx >> 4, c = (idx & 15) * 4;
      float4 v = *(const float4*)(g.Bw + (size_t)(col0 + r) * g.ldb + k0 + c);
      uint2 p; p.x = pk2(v.x, v.y); p.y = pk2(v.z, v.w);
      *(uint2*)&sB[r][c] = p;
    }
    __syncthreads();
    #pragma unroll
    for (int kk = 0; kk < 2; kk++){
      bfv8 af[4], bfr[2];
      #pragma unroll
      for (int m = 0; m < 4; m++)
        af[m] = *(const bfv8*)&sA[wr + m*16 + (lane & 15)][kk*32 + (lane >> 4) * 8];
      #pragma unroll
      for (int n = 0; n < 2; n++)
        bfr[n] = *(const bfv8*)&sB[wc + n*16 + (lane & 15)][kk*32 + (lane >> 4) * 8];
      #pragma unroll
      for (int m = 0; m < 4; m++)
        #pragma unroll
        for (int n = 0; n < 2; n++)
          acc[m][n] = __builtin_amdgcn_mfma_f32_16x16x32_bf16(af[m], bfr[n], acc[m][n], 0, 0, 0);
    }
    __syncthreads();
  }

  #pragma unroll
  for (int m = 0; m < 4; m++){
    int rbase = row0 + wr + m*16 + (lane >> 4) * 4;
    #pragma unroll
    for (int n = 0; n < 2; n++){
      int col = col0 + wc + n*16 + (lane & 15);
      #pragma unroll
      for (int j = 0; j < 4; j++){
        float v = acc[m][n][j];
        size_t o = (size_t)(rbase + j) * g.ldc + col;
        switch (g.epi){
          case 0: g.Cf[o] = v; break;
          case 1: g.Cb[o] = f2bf(v); break;
          case 2: {
            float sg = 1.f / (1.f + expf(-v));
            g.Cb[o] = f2bf(sg * g.aux0[o] + (1.f - sg) * g.aux1[o]);
          } break;
          case 4: g.Cf[o] += v; break;
          default: atomicAdd(&g.Cf[o], v); break;
        }
      }
    }
  }
}

// ---------- silu fuse: sbuf = silu(g)*u (bf16) ----------
__global__ __launch_bounds__(256) void flm_silu(
    const float* __restrict__ gg, const float* __restrict__ uu, u16* __restrict__ o)
{
  int i = blockIdx.x * 256 + threadIdx.x;
  float4 gv = ((const float4*)gg)[i];
  float4 uv = ((const float4*)uu)[i];
  float a = gv.x / (1.f + expf(-gv.x)) * uv.x;
  float b = gv.y / (1.f + expf(-gv.y)) * uv.y;
  float c = gv.z / (1.f + expf(-gv.z)) * uv.z;
  float d = gv.w / (1.f + expf(-gv.w)) * uv.w;
  uint2 p; p.x = pk2(a, b); p.y = pk2(c, d);
  ((uint2*)o)[i] = p;
}

// ---------- embedding gather + rmsnorm -> f32 h ----------
__global__ __launch_bounds__(256) void flm_embed(
    const int* __restrict__ x, const float* __restrict__ embed,
    const float* __restrict__ w, float* __restrict__ h)
{
  int t = blockIdx.x, tid = threadIdx.x;
  int tok = x[t];
  float4 v = ((const float4*)(embed + (size_t)tok * 1024))[tid];
  float ss = v.x*v.x + v.y*v.y + v.z*v.z + v.w*v.w;
  ss = wsum(ss);
  __shared__ float red[4];
  if ((tid & 63) == 0) red[tid >> 6] = ss;
  __syncthreads();
  float inv = rsqrtf((red[0]+red[1]+red[2]+red[3]) * (1.f/1024.f) + 1e-6f);
  float4 wv = ((const float4*)w)[tid];
  float4 o; o.x = v.x*inv*wv.x; o.y = v.y*inv*wv.y; o.z = v.z*inv*wv.z; o.w = v.w*inv*wv.w;
  ((float4*)(h + (size_t)t * 1024))[tid] = o;
}

// ---------- rmsnorm: h(f32) -> up to two bf16 outputs ----------
__global__ __launch_bounds__(256) void flm_rms(
    const float* __restrict__ h, const float* __restrict__ w1, const float* __restrict__ w2,
    u16* __restrict__ o1, u16* __restrict__ o2)
{
  int t = blockIdx.x, tid = threadIdx.x;
  float4 v = ((const float4*)(h + (size_t)t * 1024))[tid];
  float ss = v.x*v.x + v.y*v.y + v.z*v.z + v.w*v.w;
  ss = wsum(ss);
  __shared__ float red[4];
  if ((tid & 63) == 0) red[tid >> 6] = ss;
  __syncthreads();
  float inv = rsqrtf((red[0]+red[1]+red[2]+red[3]) * (1.f/1024.f) + 1e-6f);
  {
    float4 wv = ((const float4*)w1)[tid];
    uint2 p; p.x = pk2(v.x*inv*wv.x, v.y*inv*wv.y); p.y = pk2(v.z*inv*wv.z, v.w*inv*wv.w);
    ((uint2*)(o1 + (size_t)t * 1024))[tid] = p;
  }
  if (o2 != nullptr){
    float4 wv = ((const float4*)w2)[tid];
    uint2 p; p.x = pk2(v.x*inv*wv.x, v.y*inv*wv.y); p.y = pk2(v.z*inv*wv.z, v.w*inv*wv.w);
    ((uint2*)(o2 + (size_t)t * 1024))[tid] = p;
  }
}

// ---------- beta = sigmoid(h2 @ beta_w^T), [T][16] ----------
__global__ __launch_bounds__(64) void flm_beta(
    const u16* __restrict__ h2, const float* __restrict__ bw, float* __restrict__ beta)
{
  int t = blockIdx.x, lane = threadIdx.x;
  float hv[16];
  #pragma unroll
  for (int i = 0; i < 16; i++) hv[i] = bf2f(h2[(size_t)t*1024 + i*64 + lane]);
  for (int h = 0; h < 16; h++){
    float p = 0.f;
    #pragma unroll
    for (int i = 0; i < 16; i++) p += hv[i] * bw[h*1024 + i*64 + lane];
    p = wsum(p);
    if (lane == 0) beta[t*16 + h] = 1.f / (1.f + expf(-p));
  }
}

// ---------- normalize keys & queries per (t,h) over DM=64 ----------
__global__ __launch_bounds__(64) void flm_normkq(u16* __restrict__ keys, u16* __restrict__ queries)
{
  int t = blockIdx.x, h = blockIdx.y;
  u16* arr = blockIdx.z ? queries : keys;
  size_t idx = (size_t)t * 1024 + h * 64 + threadIdx.x;
  float v = bf2f(arr[idx]);
  float ss = wsum(v * v);
  float nrm = fmaxf(sqrtf(ss), 1e-12f);
  arr[idx] = f2bf(v / nrm);
}

// ---------- MFMA sliding-window attention ----------
__global__ __launch_bounds__(256) void flm_swa_mfma(const u16* __restrict__ qkv, u16* __restrict__ out)
{
  __shared__ u16 sK[64][72];
  __shared__ u16 sVt[64][72];
  __shared__ u16 sP[4][16][72];
  const int tid = threadIdx.x, lane = tid & 63, w = tid >> 6;
  const int qt = blockIdx.x, h = blockIdx.y;
  const int base = h * 64;

  bfv8 aq[2];
  {
    int qrow = qt*64 + w*16 + (lane & 15);
    #pragma unroll
    for (int kk = 0; kk < 2; kk++)
      aq[kk] = *(const bfv8*)(qkv + (size_t)qrow*3072 + base + kk*32 + (lane>>4)*8);
  }

  f32x4 acc_o[4];
  float m_r[4], l_r[4];
  #pragma unroll
  for (int n = 0; n < 4; n++) acc_o[n] = (f32x4){0.f,0.f,0.f,0.f};
  #pragma unroll
  for (int r = 0; r < 4; r++){ m_r[r] = -1e30f; l_r[r] = 0.f; }

  const int jt0 = (qt >= 4) ? qt - 4 : 0;
  const int ri = w*16 + (lane>>4)*4;

  for (int jt = qt; jt >= jt0; jt--){
    #pragma unroll
    for (int i = 0; i < 2; i++){
      int idx = tid + i*256;
      int r = idx >> 3, c = (idx & 7) * 8;
      uint4 kv = *(const uint4*)(qkv + (size_t)(jt*64+r)*3072 + 1024 + base + c);
      *(uint4*)&sK[r][c] = kv;
      uint4 vv = *(const uint4*)(qkv + (size_t)(jt*64+r)*3072 + 2048 + base + c);
      u16 tmp[8]; *(uint4*)tmp = vv;
      #pragma unroll
      for (int e = 0; e < 8; e++) sVt[c+e][r] = tmp[e];
    }
    __syncthreads();

    f32x4 sv[4];
    #pragma unroll
    for (int n = 0; n < 4; n++) sv[n] = (f32x4){0.f,0.f,0.f,0.f};
    #pragma unroll
    for (int kk = 0; kk < 2; kk++){
      #pragma unroll
      for (int n = 0; n < 4; n++){
        bfv8 bk = *(const bfv8*)&sK[n*16 + (lane & 15)][(lane>>4)*8 + kk*32];
        sv[n] = __builtin_amdgcn_mfma_f32_16x16x32_bf16(aq[kk], bk, sv[n], 0, 0, 0);
      }
    }
    #pragma unroll
    for (int n = 0; n < 4; n++){
      int cj = n*16 + (lane & 15);
      #pragma unroll
      for (int r = 0; r < 4; r++){
        float s = sv[n][r] * 0.125f;
        if (jt == qt)      { if (cj > ri + r) s = -1e30f; }
        else if (jt == jt0 && qt - jt0 == 4) { if (cj <= ri + r) s = -1e30f; }
        sv[n][r] = s;
      }
    }
    float pv[4][4], scl[4];
    #pragma unroll
    for (int r = 0; r < 4; r++){
      float mx = -1e30f;
      #pragma unroll
      for (int n = 0; n < 4; n++) mx = fmaxf(mx, sv[n][r]);
      #pragma unroll
      for (int m = 1; m < 16; m <<= 1) mx = fmaxf(mx, __shfl_xor(mx, m, 64));
      float mn = fmaxf(m_r[r], mx);
      float sc = expf(m_r[r] - mn);
      m_r[r] = mn; scl[r] = sc;
      float rs = 0.f;
      #pragma unroll
      for (int n = 0; n < 4; n++){ float p = expf(sv[n][r] - mn); pv[n][r] = p; rs += p; }
      #pragma unroll
      for (int m = 1; m < 16; m <<= 1) rs += __shfl_xor(rs, m, 64);
      l_r[r] = l_r[r] * sc + rs;
    }
    #pragma unroll
    for (int n = 0; n < 4; n++){
      #pragma unroll
      for (int r = 0; r < 4; r++){
        acc_o[n][r] *= scl[r];
        sP[w][(lane>>4)*4 + r][n*16 + (lane & 15)] = f2bf(pv[n][r]);
      }
    }
    #pragma unroll
    for (int kk = 0; kk < 2; kk++){
      bfv8 ap = *(const bfv8*)&sP[w][lane & 15][(lane>>4)*8 + kk*32];
      #pragma unroll
      for (int n = 0; n < 4; n++){
        bfv8 bv = *(const bfv8*)&sVt[n*16 + (lane & 15)][(lane>>4)*8 + kk*32];
        acc_o[n] = __builtin_amdgcn_mfma_f32_16x16x32_bf16(ap, bv, acc_o[n], 0, 0, 0);
      }
    }
    __syncthreads();
  }

  #pragma unroll
  for (int n = 0; n < 4; n++){
    int col = base + n*16 + (lane & 15);
    #pragma unroll
    for (int r = 0; r < 4; r++){
      int row = qt*64 + ri + r;
      out[(size_t)row*1024 + col] = f2bf(acc_o[n][r] / l_r[r]);
    }
  }
}

// ---------- MFMA delta rule ----------
__global__ __launch_bounds__(256) void flm_delta_mfma(
    const u16* __restrict__ keys, const u16* __restrict__ values, const u16* __restrict__ queries,
    const float* __restrict__ beta, u16* __restrict__ out)
{
  __shared__ u16 sK[64][72];
  __shared__ u16 sVt[64][72];
  __shared__ u16 sP[4][16][72];
  const int tid = threadIdx.x, lane = tid & 63, w = tid >> 6;
  const int qt = blockIdx.x, h = blockIdx.y;
  const int base = h * 64;

  bfv8 aq[2];
  {
    int qrow = qt*64 + w*16 + (lane & 15);
    #pragma unroll
    for (int kk = 0; kk < 2; kk++)
      aq[kk] = *(const bfv8*)(queries + (size_t)qrow*1024 + base + kk*32 + (lane>>4)*8);
  }

  f32x4 acc_o[4];
  #pragma unroll
  for (int n = 0; n < 4; n++) acc_o[n] = (f32x4){0.f,0.f,0.f,0.f};
  const int ri = w*16 + (lane>>4)*4;

  for (int jt = qt; jt < 16; jt++){
    #pragma unroll
    for (int i = 0; i < 2; i++){
      int idx = tid + i*256;
      int r = idx >> 3, c = (idx & 7) * 8;
      uint4 kv = *(const uint4*)(keys + (size_t)(jt*64+r)*1024 + base + c);
      *(uint4*)&sK[r][c] = kv;
      uint4 vv = *(const uint4*)(values + (size_t)(jt*64+r)*1024 + base + c);
      u16 tmp[8]; *(uint4*)tmp = vv;
      #pragma unroll
      for (int e = 0; e < 8; e++) sVt[c+e][r] = tmp[e];
    }
    __syncthreads();

    f32x4 sv[4];
    #pragma unroll
    for (int n = 0; n < 4; n++) sv[n] = (f32x4){0.f,0.f,0.f,0.f};
    #pragma unroll
    for (int kk = 0; kk < 2; kk++){
      #pragma unroll
      for (int n = 0; n < 4; n++){
        bfv8 bk = *(const bfv8*)&sK[n*16 + (lane & 15)][(lane>>4)*8 + kk*32];
        sv[n] = __builtin_amdgcn_mfma_f32_16x16x32_bf16(aq[kk], bk, sv[n], 0, 0, 0);
      }
    }
    #pragma unroll
    for (int n = 0; n < 4; n++){
      int cj = n*16 + (lane & 15);
      #pragma unroll
      for (int r = 0; r < 4; r++){
        float p = sv[n][r] * 0.125f;
        if (jt == qt && cj < ri + r) p = 0.f;
        sP[w][(lane>>4)*4 + r][n*16 + (lane & 15)] = f2bf(p);
      }
    }
    #pragma unroll
    for (int kk = 0; kk < 2; kk++){
      bfv8 ap = *(const bfv8*)&sP[w][lane & 15][(lane>>4)*8 + kk*32];
      #pragma unroll
      for (int n = 0; n < 4; n++){
        bfv8 bv = *(const bfv8*)&sVt[n*16 + (lane & 15)][(lane>>4)*8 + kk*32];
        acc_o[n] = __builtin_amdgcn_mfma_f32_16x16x32_bf16(ap, bv, acc_o[n], 0, 0, 0);
      }
    }
    __syncthreads();
  }

  #pragma unroll
  for (int n = 0; n < 4; n++){
    int col = base + n*16 + (lane & 15);
    #pragma unroll
    for (int r = 0; r < 4; r++){
      int row = qt*64 + ri + r;
      float b = beta[row*16 + h];
      float v = bf2f(values[(size_t)row*1024 + col]);
      out[(size_t)row*1024 + col] = f2bf(acc_o[n][r] + b * v);
    }
  }
}

// ---------- host helpers ----------
static GDesc mkd(const u16* A, int lda, const float* Bw, int ldb,
                 float* Cf, u16* Cb, int ldc, const float* a0, const float* a1,
                 int kbeg, int kend, int blk0, int epi){
  GDesc d; d.A=A; d.Bw=Bw; d.Cf=Cf; d.Cb=Cb; d.aux0=a0; d.aux1=a1;
  d.lda=lda; d.ldb=ldb; d.ldc=ldc; d.kbeg=kbeg; d.kend=kend; d.blk0=blk0; d.epi=epi; d.pad=0;
  return d;
}

extern "C" void kernel_launch(void* const* d_in, const int* in_sizes, int n_in,
                              void* d_out, int out_size, void* d_ws, size_t ws_size,
                              hipStream_t stream)
{
  (void)in_sizes; (void)n_in; (void)out_size; (void)ws_size;
  const int*   x        = (const int*)d_in[0];
  const float* embed    = (const float*)d_in[1];
  const float* ln_in_w  = (const float*)d_in[2];
  const float* ln1_w    = (const float*)d_in[3];
  const float* lnd_w    = (const float*)d_in[4];
  const float* qkv_w    = (const float*)d_in[5];
  const float* swa_out_w= (const float*)d_in[6];
  const float* k_w      = (const float*)d_in[7];
  const float* v_w      = (const float*)d_in[8];
  const float* q_w      = (const float*)d_in[9];
  const float* beta_w   = (const float*)d_in[10];
  const float* mem_out_w= (const float*)d_in[11];
  const float* gate_w   = (const float*)d_in[12];
  const float* comb_w   = (const float*)d_in[13];
  const float* ln2_w    = (const float*)d_in[14];
  const float* wg       = (const float*)d_in[15];
  const float* wu       = (const float*)d_in[16];
  const float* wo       = (const float*)d_in[17];
  const float* ln_out_w = (const float*)d_in[18];
  float* out = (float*)d_out;

  char* ws = (char*)d_ws;
  const size_t KB = 1024, MB = 1u << 20;
  // layout (MB): h 0-4 | h1 4-6 | h2 6-8 | qkvb 8-14 | keys 14-16 | values 16-18
  // | queries 18-20 | beta 20 | attn 20.25-22.25 | delt 22.25-24.25 | localb 24.25-28.25
  // | globb 28.25-32.25 | mcomb 32.25-34.25 | hn 36-38
  // FFN phase reuse: g 4-20 | u 20-36 | sbuf 36-44.   peak 44 MB
  float* h       = (float*)(ws + 0);
  u16*   h1      = (u16*)  (ws + 4*MB);
  u16*   h2      = (u16*)  (ws + 6*MB);
  u16*   qkvb    = (u16*)  (ws + 8*MB);
  u16*   keys    = (u16*)  (ws + 14*MB);
  u16*   values  = (u16*)  (ws + 16*MB);
  u16*   queries = (u16*)  (ws + 18*MB);
  float* beta    = (float*)(ws + 20*MB);
  u16*   attn    = (u16*)  (ws + 20*MB + 256*KB);
  u16*   delt    = (u16*)  (ws + 22*MB + 256*KB);
  float* localb  = (float*)(ws + 24*MB + 256*KB);
  float* globb   = (float*)(ws + 28*MB + 256*KB);
  u16*   mcomb   = (u16*)  (ws + 32*MB + 256*KB);
  u16*   hn      = (u16*)  (ws + 36*MB);
  float* g       = (float*)(ws + 4*MB);
  float* u       = (float*)(ws + 20*MB);
  u16*   sbuf    = (u16*)  (ws + 36*MB);

  flm_embed<<<1024, 256, 0, stream>>>(x, embed, ln_in_w, h);

  for (int l = 0; l < 4; l++){
    flm_rms<<<1024, 256, 0, stream>>>(h, ln1_w + l*1024, lnd_w + l*1024, h1, h2);

    // batch1: qkv (192 blk) + k,v,q (64 each) = 384
    {
      GBatch gb;
      gb.d[0] = mkd(h1, 1024, qkv_w + (size_t)l*3072*1024, 1024, nullptr, qkvb, 3072,
                    nullptr, nullptr, 0, 1024, 0, 1);
      gb.d[1] = mkd(h2, 1024, k_w + (size_t)l*1024*1024, 1024, nullptr, keys, 1024,
                    nullptr, nullptr, 0, 1024, 192, 1);
      gb.d[2] = mkd(h2, 1024, v_w + (size_t)l*1024*1024, 1024, nullptr, values, 1024,
                    nullptr, nullptr, 0, 1024, 256, 1);
      gb.d[3] = mkd(h2, 1024, q_w + (size_t)l*1024*1024, 1024, nullptr, queries, 1024,
                    nullptr, nullptr, 0, 1024, 320, 1);
      gb.ng = 4; gb.total = 384;
      flm_mgemm<<<384, 512, 0, stream>>>(gb);
    }
    flm_beta<<<1024, 64, 0, stream>>>(h2, beta_w + (size_t)l*16*1024, beta);
    flm_normkq<<<dim3(1024, 16, 2), 64, 0, stream>>>(keys, queries);
    flm_swa_mfma<<<dim3(16, 16), 256, 0, stream>>>(qkvb, attn);
    flm_delta_mfma<<<dim3(16, 16), 256, 0, stream>>>(keys, values, queries, beta, delt);

    // batch2: swa_out + mem_out (64 each) = 128
    {
      GBatch gb;
      gb.d[0] = mkd(attn, 1024, swa_out_w + (size_t)l*1024*1024, 1024, localb, nullptr, 1024,
                    nullptr, nullptr, 0, 1024, 0, 0);
      gb.d[1] = mkd(delt, 1024, mem_out_w + (size_t)l*1024*1024, 1024, globb, nullptr, 1024,
                    nullptr, nullptr, 0, 1024, 64, 0);
      gb.d[2] = gb.d[1]; gb.d[2].blk0 = 0x7fffffff;
      gb.d[3] = gb.d[2];
      gb.ng = 2; gb.total = 128;
      flm_mgemm<<<128, 512, 0, stream>>>(gb);
    }
    // gate (64)
    {
      GBatch gb;
      gb.d[0] = mkd(h1, 1024, gate_w + (size_t)l*1024*1024, 1024, nullptr, mcomb, 1024,
                    localb, globb, 0, 1024, 0, 2);
      gb.d[1] = gb.d[0]; gb.d[1].blk0 = 0x7fffffff;
      gb.d[2] = gb.d[1]; gb.d[3] = gb.d[1];
      gb.ng = 1; gb.total = 64;
      flm_mgemm<<<64, 512, 0, stream>>>(gb);
    }
    // comb: split-K x2, atomicAdd into live h = 128 blocks
    {
      GBatch gb;
      gb.d[0] = mkd(mcomb, 1024, comb_w + (size_t)l*1024*1024, 1024, h, nullptr, 1024,
                    nullptr, nullptr, 0, 512, 0, 5);
      gb.d[1] = mkd(mcomb, 1024, comb_w + (size_t)l*1024*1024, 1024, h, nullptr, 1024,
                    nullptr, nullptr, 512, 1024, 64, 5);
      gb.d[2] = gb.d[1]; gb.d[2].blk0 = 0x7fffffff;
      gb.d[3] = gb.d[2];
      gb.ng = 2; gb.total = 128;
      flm_mgemm<<<128, 512, 0, stream>>>(gb);
    }
    flm_rms<<<1024, 256, 0, stream>>>(h, ln2_w + l*1024, nullptr, hn, nullptr);
    // batch3: wg -> g, wu -> u (256 each) = 512
    {
      GBatch gb;
      gb.d[0] = mkd(hn, 1024, wg + (size_t)l*4096*1024, 1024, g, nullptr, 4096,
                    nullptr, nullptr, 0, 1024, 0, 0);
      gb.d[1] = mkd(hn, 1024, wu + (size_t)l*4096*1024, 1024, u, nullptr, 4096,
                    nullptr, nullptr, 0, 1024, 256, 0);
      gb.d[2] = gb.d[1]; gb.d[2].blk0 = 0x7fffffff;
      gb.d[3] = gb.d[2];
      gb.ng = 2; gb.total = 512;
      flm_mgemm<<<512, 512, 0, stream>>>(gb);
    }
    flm_silu<<<4096, 256, 0, stream>>>(g, u, sbuf);
    // wo: split-K x4, atomicAdd into h = 256 blocks
    {
      GBatch gb;
      #pragma unroll
      for (int s = 0; s < 4; s++)
        gb.d[s] = mkd(sbuf, 4096, wo + (size_t)l*1024*4096, 4096, h, nullptr, 1024,
                      nullptr, nullptr, s*1024, (s+1)*1024, s*64, 5);
      gb.ng = 4; gb.total = 256;
      flm_mgemm<<<256, 512, 0, stream>>>(gb);
    }
  }

  flm_rms<<<1024, 256, 0, stream>>>(h, ln_out_w, nullptr, hn, nullptr);
  // head: 250 col-tiles x 8 row-tiles = 2000 blocks
  {
    GBatch gb;
    gb.d[0] = mkd(hn, 1024, embed, 1024, out, nullptr, 32000,
                  nullptr, nullptr, 0, 1024, 0, 0);
    gb.d[1] = gb.d[0]; gb.d[1].blk0 = 0x7fffffff;
    gb.d[2] = gb.d[1]; gb.d[3] = gb.d[1];
    gb.ng = 1; gb.total = 2000;
    flm_mgemm<<<2000, 512, 0, stream>>>(gb);
  }
}

// Round 4
// 1018.082 us; speedup vs baseline: 6.2296x; 1.2603x over previous
//
#include <hip/hip_runtime.h>

typedef unsigned short u16;
typedef unsigned int   u32;
typedef __attribute__((ext_vector_type(8))) __bf16 bfv8;
typedef __attribute__((ext_vector_type(4))) float  f32x4;

// ---------- helpers ----------
__device__ __forceinline__ u16 f2bf(float f){
  u32 u = __builtin_bit_cast(u32, f);
  return (u16)((u + 0x7FFFu + ((u >> 16) & 1u)) >> 16);   // RNE
}
__device__ __forceinline__ float bf2f(u16 b){
  return __builtin_bit_cast(float, ((u32)b) << 16);
}
__device__ __forceinline__ u32 pk2(float a, float b){
  return (u32)f2bf(a) | ((u32)f2bf(b) << 16);
}
__device__ __forceinline__ float wsum(float v){
  #pragma unroll
  for (int m = 32; m > 0; m >>= 1) v += __shfl_xor(v, m, 64);
  return v;
}
__device__ __forceinline__ void gload16(const void* g, void* l){
  __builtin_amdgcn_global_load_lds((const __attribute__((address_space(1))) void*)g,
                                   (__attribute__((address_space(3))) void*)l, 16, 0, 0);
}

// ---------- weight f32 -> bf16 conversion ----------
struct CBatch { const float* s[12]; long long p4[13]; u16* dst; };
__global__ __launch_bounds__(256) void flm_conv(CBatch cb)
{
  long long total = cb.p4[12];
  for (long long i = (long long)blockIdx.x * 256 + threadIdx.x; i < total;
       i += (long long)gridDim.x * 256){
    int t = 0;
    for (int j = 1; j < 12; j++) if (i >= cb.p4[j]) t = j;
    long long il = i - cb.p4[t];
    float4 v = ((const float4*)cb.s[t])[il];
    uint2 p; p.x = pk2(v.x, v.y); p.y = pk2(v.z, v.w);
    ((uint2*)cb.dst)[i] = p;
  }
}

// ---------- multi-GEMM ----------
// C[rows][cols] = A[*,K](bf16) * W[col,K]^T. BW=true: W is bf16, staged via
// global_load_lds with XOR-swizzle (linear LDS dest + inverse-swizzled global
// src + swizzled ds_read -- rule #21). BW=false: W is f32, staged with cvt.
// epi: 0 = f32 store, 1 = bf16 store, 5 = f32 atomicAdd
struct GDesc {
  const u16* A; const float* Bw; float* Cf; u16* Cb;
  int lda, ldb, ldc, kbeg, kend, blk0, epi, pad;
};
struct GBatch { GDesc d[6]; int ng, total; };

template<bool BW>
__global__ __launch_bounds__(512) void flm_mgemm(GBatch gb)
{
  constexpr int LDK = BW ? 64 : 72;
  __shared__ u16 sA[128][LDK];
  __shared__ u16 sB[128][LDK];
  const int tid = threadIdx.x, lane = tid & 63, w = tid >> 6;

  const int T = gb.total, bid = blockIdx.x;
  const int q8 = T >> 3, r8 = T & 7, xc = bid & 7, of = bid >> 3;
  const int lin = (xc < r8 ? xc * (q8 + 1) : r8 * (q8 + 1) + (xc - r8) * q8) + of;
  int di = 0;
  #pragma unroll
  for (int i = 1; i < 6; i++) if (i < gb.ng && lin >= gb.d[i].blk0) di = i;
  const GDesc g = gb.d[di];
  const int local = lin - g.blk0;
  const int row0 = (local & 7) * 128;
  const int col0 = (local >> 3) * 128;
  const int wr = (w >> 2) * 64, wc = (w & 3) * 32;

  f32x4 acc[4][2];
  #pragma unroll
  for (int m = 0; m < 4; m++)
    #pragma unroll
    for (int n = 0; n < 2; n++)
      acc[m][n] = (f32x4){0.f, 0.f, 0.f, 0.f};

  const int csw = ((lane & 7) ^ (lane >> 3)) * 8;   // inverse-swizzled src col (elems)
  const u16* B16 = (const u16*)g.Bw;

  for (int k0 = g.kbeg; k0 < g.kend; k0 += 64){
    if constexpr (BW){
      const u16* a0 = g.A + (size_t)(row0 + w*16 + (lane>>3)) * g.lda + k0 + csw;
      const u16* b0 = B16 + (size_t)(col0 + w*16 + (lane>>3)) * g.ldb + k0 + csw;
      gload16(a0,                     &sA[w*16    ][0]);
      gload16(a0 + (size_t)8*g.lda,   &sA[w*16 + 8][0]);
      gload16(b0,                     &sB[w*16    ][0]);
      gload16(b0 + (size_t)8*g.ldb,   &sB[w*16 + 8][0]);
    } else {
      #pragma unroll
      for (int i = 0; i < 2; i++){
        int idx = tid + i * 512;
        int r = idx >> 3, c = (idx & 7) * 8;
        *(uint4*)&sA[r][c] = *(const uint4*)(g.A + (size_t)(row0 + r) * g.lda + k0 + c);
      }
      #pragma unroll
      for (int i = 0; i < 4; i++){
        int idx = tid + i * 512;
        int r = idx >> 4, c = (idx & 15) * 4;
        float4 v = *(const float4*)(g.Bw + (size_t)(col0 + r) * g.ldb + k0 + c);
        uint2 p; p.x = pk2(v.x, v.y); p.y = pk2(v.z, v.w);
        *(uint2*)&sB[r][c] = p;
      }
    }
    __syncthreads();
    #pragma unroll
    for (int kk = 0; kk < 2; kk++){
      bfv8 af[4], bfr[2];
      #pragma unroll
      for (int m = 0; m < 4; m++){
        int row = wr + m*16 + (lane & 15);
        if constexpr (BW){
          int slot = (kk*4 + (lane >> 4)) ^ (row & 7);
          af[m] = *(const bfv8*)((const char*)sA + row*128 + slot*16);
        } else {
          af[m] = *(const bfv8*)&sA[row][kk*32 + (lane >> 4) * 8];
        }
      }
      #pragma unroll
      for (int n = 0; n < 2; n++){
        int row = wc + n*16 + (lane & 15);
        if constexpr (BW){
          int slot = (kk*4 + (lane >> 4)) ^ (row & 7);
          bfr[n] = *(const bfv8*)((const char*)sB + row*128 + slot*16);
        } else {
          bfr[n] = *(const bfv8*)&sB[row][kk*32 + (lane >> 4) * 8];
        }
      }
      #pragma unroll
      for (int m = 0; m < 4; m++)
        #pragma unroll
        for (int n = 0; n < 2; n++)
          acc[m][n] = __builtin_amdgcn_mfma_f32_16x16x32_bf16(af[m], bfr[n], acc[m][n], 0, 0, 0);
    }
    __syncthreads();
  }

  #pragma unroll
  for (int m = 0; m < 4; m++){
    int rbase = row0 + wr + m*16 + (lane >> 4) * 4;
    #pragma unroll
    for (int n = 0; n < 2; n++){
      int col = col0 + wc + n*16 + (lane & 15);
      #pragma unroll
      for (int j = 0; j < 4; j++){
        float v = acc[m][n][j];
        size_t o = (size_t)(rbase + j) * g.ldc + col;
        switch (g.epi){
          case 0: g.Cf[o] = v; break;
          case 1: g.Cb[o] = f2bf(v); break;
          default: atomicAdd(&g.Cf[o], v); break;
        }
      }
    }
  }
}

// ---------- mix: mcomb = sig(gate)*local + (1-sig)*global ----------
__global__ __launch_bounds__(256) void flm_mix(
    const float* __restrict__ gr, const float* __restrict__ lo,
    const float* __restrict__ gl, u16* __restrict__ o)
{
  int i = blockIdx.x * 256 + threadIdx.x;
  float4 gv = ((const float4*)gr)[i];
  float4 lv = ((const float4*)lo)[i];
  float4 bv = ((const float4*)gl)[i];
  float sx = 1.f/(1.f+expf(-gv.x)), sy = 1.f/(1.f+expf(-gv.y));
  float sz = 1.f/(1.f+expf(-gv.z)), sw = 1.f/(1.f+expf(-gv.w));
  uint2 p;
  p.x = pk2(sx*lv.x + (1.f-sx)*bv.x, sy*lv.y + (1.f-sy)*bv.y);
  p.y = pk2(sz*lv.z + (1.f-sz)*bv.z, sw*lv.w + (1.f-sw)*bv.w);
  ((uint2*)o)[i] = p;
}

// ---------- silu fuse: sbuf = silu(g)*u (bf16) ----------
__global__ __launch_bounds__(256) void flm_silu(
    const float* __restrict__ gg, const float* __restrict__ uu, u16* __restrict__ o)
{
  int i = blockIdx.x * 256 + threadIdx.x;
  float4 gv = ((const float4*)gg)[i];
  float4 uv = ((const float4*)uu)[i];
  float a = gv.x / (1.f + expf(-gv.x)) * uv.x;
  float b = gv.y / (1.f + expf(-gv.y)) * uv.y;
  float c = gv.z / (1.f + expf(-gv.z)) * uv.z;
  float d = gv.w / (1.f + expf(-gv.w)) * uv.w;
  uint2 p; p.x = pk2(a, b); p.y = pk2(c, d);
  ((uint2*)o)[i] = p;
}

// ---------- embedding gather + rmsnorm -> f32 h ----------
__global__ __launch_bounds__(256) void flm_embed(
    const int* __restrict__ x, const float* __restrict__ embed,
    const float* __restrict__ w, float* __restrict__ h)
{
  int t = blockIdx.x, tid = threadIdx.x;
  int tok = x[t];
  float4 v = ((const float4*)(embed + (size_t)tok * 1024))[tid];
  float ss = v.x*v.x + v.y*v.y + v.z*v.z + v.w*v.w;
  ss = wsum(ss);
  __shared__ float red[4];
  if ((tid & 63) == 0) red[tid >> 6] = ss;
  __syncthreads();
  float inv = rsqrtf((red[0]+red[1]+red[2]+red[3]) * (1.f/1024.f) + 1e-6f);
  float4 wv = ((const float4*)w)[tid];
  float4 o; o.x = v.x*inv*wv.x; o.y = v.y*inv*wv.y; o.z = v.z*inv*wv.z; o.w = v.w*inv*wv.w;
  ((float4*)(h + (size_t)t * 1024))[tid] = o;
}

// ---------- rmsnorm: h(f32) -> up to two bf16 outputs ----------
__global__ __launch_bounds__(256) void flm_rms(
    const float* __restrict__ h, const float* __restrict__ w1, const float* __restrict__ w2,
    u16* __restrict__ o1, u16* __restrict__ o2)
{
  int t = blockIdx.x, tid = threadIdx.x;
  float4 v = ((const float4*)(h + (size_t)t * 1024))[tid];
  float ss = v.x*v.x + v.y*v.y + v.z*v.z + v.w*v.w;
  ss = wsum(ss);
  __shared__ float red[4];
  if ((tid & 63) == 0) red[tid >> 6] = ss;
  __syncthreads();
  float inv = rsqrtf((red[0]+red[1]+red[2]+red[3]) * (1.f/1024.f) + 1e-6f);
  {
    float4 wv = ((const float4*)w1)[tid];
    uint2 p; p.x = pk2(v.x*inv*wv.x, v.y*inv*wv.y); p.y = pk2(v.z*inv*wv.z, v.w*inv*wv.w);
    ((uint2*)(o1 + (size_t)t * 1024))[tid] = p;
  }
  if (o2 != nullptr){
    float4 wv = ((const float4*)w2)[tid];
    uint2 p; p.x = pk2(v.x*inv*wv.x, v.y*inv*wv.y); p.y = pk2(v.z*inv*wv.z, v.w*inv*wv.w);
    ((uint2*)(o2 + (size_t)t * 1024))[tid] = p;
  }
}

// ---------- beta = sigmoid(h2 @ beta_w^T), [T][16] ----------
__global__ __launch_bounds__(64) void flm_beta(
    const u16* __restrict__ h2, const float* __restrict__ bw, float* __restrict__ beta)
{
  int t = blockIdx.x, lane = threadIdx.x;
  float hv[16];
  #pragma unroll
  for (int i = 0; i < 16; i++) hv[i] = bf2f(h2[(size_t)t*1024 + i*64 + lane]);
  for (int h = 0; h < 16; h++){
    float p = 0.f;
    #pragma unroll
    for (int i = 0; i < 16; i++) p += hv[i] * bw[h*1024 + i*64 + lane];
    p = wsum(p);
    if (lane == 0) beta[t*16 + h] = 1.f / (1.f + expf(-p));
  }
}

// ---------- normalize keys & queries per (t,h) over DM=64 ----------
__global__ __launch_bounds__(64) void flm_normkq(u16* __restrict__ keys, u16* __restrict__ queries)
{
  int t = blockIdx.x, h = blockIdx.y;
  u16* arr = blockIdx.z ? queries : keys;
  size_t idx = (size_t)t * 1024 + h * 64 + threadIdx.x;
  float v = bf2f(arr[idx]);
  float ss = wsum(v * v);
  float nrm = fmaxf(sqrtf(ss), 1e-12f);
  arr[idx] = f2bf(v / nrm);
}

// ---------- merged attention: z=0 -> SWA, z=1 -> delta ----------
__global__ __launch_bounds__(256) void flm_attn(
    const u16* __restrict__ qkv,
    const u16* __restrict__ keys, const u16* __restrict__ values, const u16* __restrict__ queries,
    const float* __restrict__ beta, u16* __restrict__ aout, u16* __restrict__ dout)
{
  __shared__ u16 sK[64][72];
  __shared__ u16 sVt[64][72];
  __shared__ u16 sP[4][16][72];
  const int tid = threadIdx.x, lane = tid & 63, w = tid >> 6;
  const int qt = blockIdx.x, h = blockIdx.y;
  const int base = h * 64;
  const int ri = w*16 + (lane>>4)*4;

  if (blockIdx.z == 0){
    // ---- sliding-window attention ----
    bfv8 aq[2];
    {
      int qrow = qt*64 + w*16 + (lane & 15);
      #pragma unroll
      for (int kk = 0; kk < 2; kk++)
        aq[kk] = *(const bfv8*)(qkv + (size_t)qrow*3072 + base + kk*32 + (lane>>4)*8);
    }
    f32x4 acc_o[4];
    float m_r[4], l_r[4];
    #pragma unroll
    for (int n = 0; n < 4; n++) acc_o[n] = (f32x4){0.f,0.f,0.f,0.f};
    #pragma unroll
    for (int r = 0; r < 4; r++){ m_r[r] = -1e30f; l_r[r] = 0.f; }
    const int jt0 = (qt >= 4) ? qt - 4 : 0;

    for (int jt = qt; jt >= jt0; jt--){
      #pragma unroll
      for (int i = 0; i < 2; i++){
        int idx = tid + i*256;
        int r = idx >> 3, c = (idx & 7) * 8;
        uint4 kv = *(const uint4*)(qkv + (size_t)(jt*64+r)*3072 + 1024 + base + c);
        *(uint4*)&sK[r][c] = kv;
        uint4 vv = *(const uint4*)(qkv + (size_t)(jt*64+r)*3072 + 2048 + base + c);
        u16 tmp[8]; *(uint4*)tmp = vv;
        #pragma unroll
        for (int e = 0; e < 8; e++) sVt[c+e][r] = tmp[e];
      }
      __syncthreads();

      f32x4 sv[4];
      #pragma unroll
      for (int n = 0; n < 4; n++) sv[n] = (f32x4){0.f,0.f,0.f,0.f};
      #pragma unroll
      for (int kk = 0; kk < 2; kk++){
        #pragma unroll
        for (int n = 0; n < 4; n++){
          bfv8 bk = *(const bfv8*)&sK[n*16 + (lane & 15)][(lane>>4)*8 + kk*32];
          sv[n] = __builtin_amdgcn_mfma_f32_16x16x32_bf16(aq[kk], bk, sv[n], 0, 0, 0);
        }
      }
      #pragma unroll
      for (int n = 0; n < 4; n++){
        int cj = n*16 + (lane & 15);
        #pragma unroll
        for (int r = 0; r < 4; r++){
          float s = sv[n][r] * 0.125f;
          if (jt == qt)      { if (cj > ri + r) s = -1e30f; }
          else if (jt == jt0 && qt - jt0 == 4) { if (cj <= ri + r) s = -1e30f; }
          sv[n][r] = s;
        }
      }
      float pv[4][4], scl[4];
      #pragma unroll
      for (int r = 0; r < 4; r++){
        float mx = -1e30f;
        #pragma unroll
        for (int n = 0; n < 4; n++) mx = fmaxf(mx, sv[n][r]);
        #pragma unroll
        for (int m = 1; m < 16; m <<= 1) mx = fmaxf(mx, __shfl_xor(mx, m, 64));
        float mn = fmaxf(m_r[r], mx);
        float sc = expf(m_r[r] - mn);
        m_r[r] = mn; scl[r] = sc;
        float rs = 0.f;
        #pragma unroll
        for (int n = 0; n < 4; n++){ float p = expf(sv[n][r] - mn); pv[n][r] = p; rs += p; }
        #pragma unroll
        for (int m = 1; m < 16; m <<= 1) rs += __shfl_xor(rs, m, 64);
        l_r[r] = l_r[r] * sc + rs;
      }
      #pragma unroll
      for (int n = 0; n < 4; n++){
        #pragma unroll
        for (int r = 0; r < 4; r++){
          acc_o[n][r] *= scl[r];
          sP[w][(lane>>4)*4 + r][n*16 + (lane & 15)] = f2bf(pv[n][r]);
        }
      }
      #pragma unroll
      for (int kk = 0; kk < 2; kk++){
        bfv8 ap = *(const bfv8*)&sP[w][lane & 15][(lane>>4)*8 + kk*32];
        #pragma unroll
        for (int n = 0; n < 4; n++){
          bfv8 bv = *(const bfv8*)&sVt[n*16 + (lane & 15)][(lane>>4)*8 + kk*32];
          acc_o[n] = __builtin_amdgcn_mfma_f32_16x16x32_bf16(ap, bv, acc_o[n], 0, 0, 0);
        }
      }
      __syncthreads();
    }

    #pragma unroll
    for (int n = 0; n < 4; n++){
      int col = base + n*16 + (lane & 15);
      #pragma unroll
      for (int r = 0; r < 4; r++){
        int row = qt*64 + ri + r;
        aout[(size_t)row*1024 + col] = f2bf(acc_o[n][r] / l_r[r]);
      }
    }
  } else {
    // ---- delta rule ----
    bfv8 aq[2];
    {
      int qrow = qt*64 + w*16 + (lane & 15);
      #pragma unroll
      for (int kk = 0; kk < 2; kk++)
        aq[kk] = *(const bfv8*)(queries + (size_t)qrow*1024 + base + kk*32 + (lane>>4)*8);
    }
    f32x4 acc_o[4];
    #pragma unroll
    for (int n = 0; n < 4; n++) acc_o[n] = (f32x4){0.f,0.f,0.f,0.f};

    for (int jt = qt; jt < 16; jt++){
      #pragma unroll
      for (int i = 0; i < 2; i++){
        int idx = tid + i*256;
        int r = idx >> 3, c = (idx & 7) * 8;
        uint4 kv = *(const uint4*)(keys + (size_t)(jt*64+r)*1024 + base + c);
        *(uint4*)&sK[r][c] = kv;
        uint4 vv = *(const uint4*)(values + (size_t)(jt*64+r)*1024 + base + c);
        u16 tmp[8]; *(uint4*)tmp = vv;
        #pragma unroll
        for (int e = 0; e < 8; e++) sVt[c+e][r] = tmp[e];
      }
      __syncthreads();

      f32x4 sv[4];
      #pragma unroll
      for (int n = 0; n < 4; n++) sv[n] = (f32x4){0.f,0.f,0.f,0.f};
      #pragma unroll
      for (int kk = 0; kk < 2; kk++){
        #pragma unroll
        for (int n = 0; n < 4; n++){
          bfv8 bk = *(const bfv8*)&sK[n*16 + (lane & 15)][(lane>>4)*8 + kk*32];
          sv[n] = __builtin_amdgcn_mfma_f32_16x16x32_bf16(aq[kk], bk, sv[n], 0, 0, 0);
        }
      }
      #pragma unroll
      for (int n = 0; n < 4; n++){
        int cj = n*16 + (lane & 15);
        #pragma unroll
        for (int r = 0; r < 4; r++){
          float p = sv[n][r] * 0.125f;
          if (jt == qt && cj < ri + r) p = 0.f;
          sP[w][(lane>>4)*4 + r][n*16 + (lane & 15)] = f2bf(p);
        }
      }
      #pragma unroll
      for (int kk = 0; kk < 2; kk++){
        bfv8 ap = *(const bfv8*)&sP[w][lane & 15][(lane>>4)*8 + kk*32];
        #pragma unroll
        for (int n = 0; n < 4; n++){
          bfv8 bv = *(const bfv8*)&sVt[n*16 + (lane & 15)][(lane>>4)*8 + kk*32];
          acc_o[n] = __builtin_amdgcn_mfma_f32_16x16x32_bf16(ap, bv, acc_o[n], 0, 0, 0);
        }
      }
      __syncthreads();
    }

    #pragma unroll
    for (int n = 0; n < 4; n++){
      int col = base + n*16 + (lane & 15);
      #pragma unroll
      for (int r = 0; r < 4; r++){
        int row = qt*64 + ri + r;
        float b = beta[row*16 + h];
        float v = bf2f(values[(size_t)row*1024 + col]);
        dout[(size_t)row*1024 + col] = f2bf(acc_o[n][r] + b * v);
      }
    }
  }
}

// ---------- host helpers ----------
static GDesc mkd(const u16* A, int lda, const float* Bw, int ldb,
                 float* Cf, u16* Cb, int ldc,
                 int kbeg, int kend, int blk0, int epi){
  GDesc d; d.A=A; d.Bw=Bw; d.Cf=Cf; d.Cb=Cb;
  d.lda=lda; d.ldb=ldb; d.ldc=ldc; d.kbeg=kbeg; d.kend=kend; d.blk0=blk0; d.epi=epi; d.pad=0;
  return d;
}

extern "C" void kernel_launch(void* const* d_in, const int* in_sizes, int n_in,
                              void* d_out, int out_size, void* d_ws, size_t ws_size,
                              hipStream_t stream)
{
  (void)in_sizes; (void)n_in; (void)out_size;
  const int*   x        = (const int*)d_in[0];
  const float* embed    = (const float*)d_in[1];
  const float* ln_in_w  = (const float*)d_in[2];
  const float* ln1_w    = (const float*)d_in[3];
  const float* lnd_w    = (const float*)d_in[4];
  const float* qkv_w    = (const float*)d_in[5];
  const float* swa_out_w= (const float*)d_in[6];
  const float* k_w      = (const float*)d_in[7];
  const float* v_w      = (const float*)d_in[8];
  const float* q_w      = (const float*)d_in[9];
  const float* beta_w   = (const float*)d_in[10];
  const float* mem_out_w= (const float*)d_in[11];
  const float* gate_w   = (const float*)d_in[12];
  const float* comb_w   = (const float*)d_in[13];
  const float* ln2_w    = (const float*)d_in[14];
  const float* wg       = (const float*)d_in[15];
  const float* wu       = (const float*)d_in[16];
  const float* wo       = (const float*)d_in[17];
  const float* ln_out_w = (const float*)d_in[18];
  float* out = (float*)d_out;

  char* ws = (char*)d_ws;
  const size_t KB = 1024, MB = 1u << 20;
  // activations: h 0-4 | h1 4-6 | h2 6-8 | qkvb 8-14 | keys 14-16 | values 16-18
  // | queries 18-20 | beta 20 | attn 20.25-22.25 | delt 22.25-24.25
  // | localb 24.25-28.25 | globb 28.25-32.25 | mcomb 32.25-34.25 | hn 36-38 | gbuf 40-44
  // FFN reuse: g 4-20 | u 20-36 | sbuf 36-44.  bf16 weights at 44 MB+.
  float* h       = (float*)(ws + 0);
  u16*   h1      = (u16*)  (ws + 4*MB);
  u16*   h2      = (u16*)  (ws + 6*MB);
  u16*   qkvb    = (u16*)  (ws + 8*MB);
  u16*   keys    = (u16*)  (ws + 14*MB);
  u16*   values  = (u16*)  (ws + 16*MB);
  u16*   queries = (u16*)  (ws + 18*MB);
  float* beta    = (float*)(ws + 20*MB);
  u16*   attn    = (u16*)  (ws + 20*MB + 256*KB);
  u16*   delt    = (u16*)  (ws + 22*MB + 256*KB);
  float* localb  = (float*)(ws + 24*MB + 256*KB);
  float* globb   = (float*)(ws + 28*MB + 256*KB);
  u16*   mcomb   = (u16*)  (ws + 32*MB + 256*KB);
  u16*   hn      = (u16*)  (ws + 36*MB);
  float* gbuf    = (float*)(ws + 40*MB);
  float* g       = (float*)(ws + 4*MB);
  float* u       = (float*)(ws + 20*MB);
  u16*   sbuf    = (u16*)  (ws + 36*MB);

  // bf16 weight region
  u16* wb = (u16*)(ws + 44*MB);
  size_t off = 0; auto nx = [&](size_t n){ size_t o = off; off += n; return o; };
  const size_t nEmb = 32768000ULL, nQkv = 12582912ULL, nSq = 4194304ULL, nFf = 16777216ULL;
  u16* wemb  = wb + nx(nEmb);
  u16* wqkv  = wb + nx(nQkv);
  u16* wswa  = wb + nx(nSq);
  u16* wk    = wb + nx(nSq);
  u16* wv    = wb + nx(nSq);
  u16* wq    = wb + nx(nSq);
  u16* wmem  = wb + nx(nSq);
  u16* wgate = wb + nx(nSq);
  u16* wcomb = wb + nx(nSq);
  u16* wwg   = wb + nx(nFf);
  u16* wwu   = wb + nx(nFf);
  u16* wwo   = wb + nx(nFf);
  const size_t NEED = 44*MB + off * 2;
  const bool bw = (ws_size >= NEED);

  auto MG = [&](int nblk, GBatch& gbv){
    if (bw) flm_mgemm<true><<<nblk, 512, 0, stream>>>(gbv);
    else    flm_mgemm<false><<<nblk, 512, 0, stream>>>(gbv);
  };

  if (bw){
    CBatch cb;
    const float* srcs[12] = {embed, qkv_w, swa_out_w, k_w, v_w, q_w,
                             mem_out_w, gate_w, comb_w, wg, wu, wo};
    const size_t ns[12] = {nEmb, nQkv, nSq, nSq, nSq, nSq, nSq, nSq, nSq, nFf, nFf, nFf};
    long long acc4 = 0;
    for (int i = 0; i < 12; i++){ cb.s[i] = srcs[i]; cb.p4[i] = acc4; acc4 += (long long)(ns[i] >> 2); }
    cb.p4[12] = acc4; cb.dst = wb;
    flm_conv<<<2048, 256, 0, stream>>>(cb);
  }

  flm_embed<<<1024, 256, 0, stream>>>(x, embed, ln_in_w, h);

  for (int l = 0; l < 4; l++){
    const size_t lq = (size_t)l * 3145728, ls = (size_t)l * 1048576, lf = (size_t)l * 4194304;
    const float* Wqkv  = bw ? (const float*)(wqkv  + lq) : qkv_w     + lq;
    const float* Wk    = bw ? (const float*)(wk    + ls) : k_w       + ls;
    const float* Wv    = bw ? (const float*)(wv    + ls) : v_w       + ls;
    const float* Wq    = bw ? (const float*)(wq    + ls) : q_w       + ls;
    const float* Wswa  = bw ? (const float*)(wswa  + ls) : swa_out_w + ls;
    const float* Wmem  = bw ? (const float*)(wmem  + ls) : mem_out_w + ls;
    const float* Wgate = bw ? (const float*)(wgate + ls) : gate_w    + ls;
    const float* Wcomb = bw ? (const float*)(wcomb + ls) : comb_w    + ls;
    const float* Wwg   = bw ? (const float*)(wwg   + lf) : wg        + lf;
    const float* Wwu   = bw ? (const float*)(wwu   + lf) : wu        + lf;
    const float* Wwo   = bw ? (const float*)(wwo   + lf) : wo        + lf;

    flm_rms<<<1024, 256, 0, stream>>>(h, ln1_w + l*1024, lnd_w + l*1024, h1, h2);

    // batch1: qkv(192) + k(64) + v(64) + q(64) + gate->gbuf(64) = 448
    {
      GBatch gb;
      gb.d[0] = mkd(h1, 1024, Wqkv, 1024, nullptr, qkvb, 3072, 0, 1024, 0, 1);
      gb.d[1] = mkd(h2, 1024, Wk, 1024, nullptr, keys, 1024, 0, 1024, 192, 1);
      gb.d[2] = mkd(h2, 1024, Wv, 1024, nullptr, values, 1024, 0, 1024, 256, 1);
      gb.d[3] = mkd(h2, 1024, Wq, 1024, nullptr, queries, 1024, 0, 1024, 320, 1);
      gb.d[4] = mkd(h1, 1024, Wgate, 1024, gbuf, nullptr, 1024, 0, 1024, 384, 0);
      gb.d[5] = gb.d[4]; gb.d[5].blk0 = 0x7fffffff;
      gb.ng = 5; gb.total = 448;
      MG(448, gb);
    }
    flm_beta<<<1024, 64, 0, stream>>>(h2, beta_w + (size_t)l*16*1024, beta);
    flm_normkq<<<dim3(1024, 16, 2), 64, 0, stream>>>(keys, queries);
    flm_attn<<<dim3(16, 16, 2), 256, 0, stream>>>(qkvb, keys, values, queries, beta, attn, delt);

    // batch2: swa_out(64) + mem_out(64) = 128
    {
      GBatch gb;
      gb.d[0] = mkd(attn, 1024, Wswa, 1024, localb, nullptr, 1024, 0, 1024, 0, 0);
      gb.d[1] = mkd(delt, 1024, Wmem, 1024, globb, nullptr, 1024, 0, 1024, 64, 0);
      gb.d[2] = gb.d[1]; gb.d[2].blk0 = 0x7fffffff;
      gb.d[3] = gb.d[2]; gb.d[4] = gb.d[2]; gb.d[5] = gb.d[2];
      gb.ng = 2; gb.total = 128;
      MG(128, gb);
    }
    flm_mix<<<1024, 256, 0, stream>>>(gbuf, localb, globb, mcomb);
    // comb: split-K x2, atomicAdd into live h
    {
      GBatch gb;
      gb.d[0] = mkd(mcomb, 1024, Wcomb, 1024, h, nullptr, 1024, 0, 512, 0, 5);
      gb.d[1] = mkd(mcomb, 1024, Wcomb, 1024, h, nullptr, 1024, 512, 1024, 64, 5);
      gb.d[2] = gb.d[1]; gb.d[2].blk0 = 0x7fffffff;
      gb.d[3] = gb.d[2]; gb.d[4] = gb.d[2]; gb.d[5] = gb.d[2];
      gb.ng = 2; gb.total = 128;
      MG(128, gb);
    }
    flm_rms<<<1024, 256, 0, stream>>>(h, ln2_w + l*1024, nullptr, hn, nullptr);
    // batch3: wg -> g (256) + wu -> u (256) = 512
    {
      GBatch gb;
      gb.d[0] = mkd(hn, 1024, Wwg, 1024, g, nullptr, 4096, 0, 1024, 0, 0);
      gb.d[1] = mkd(hn, 1024, Wwu, 1024, u, nullptr, 4096, 0, 1024, 256, 0);
      gb.d[2] = gb.d[1]; gb.d[2].blk0 = 0x7fffffff;
      gb.d[3] = gb.d[2]; gb.d[4] = gb.d[2]; gb.d[5] = gb.d[2];
      gb.ng = 2; gb.total = 512;
      MG(512, gb);
    }
    flm_silu<<<4096, 256, 0, stream>>>(g, u, sbuf);
    // wo: split-K x4, atomicAdd into h
    {
      GBatch gb;
      for (int s = 0; s < 4; s++)
        gb.d[s] = mkd(sbuf, 4096, Wwo, 4096, h, nullptr, 1024, s*1024, (s+1)*1024, s*64, 5);
      gb.d[4] = gb.d[3]; gb.d[4].blk0 = 0x7fffffff;
      gb.d[5] = gb.d[4];
      gb.ng = 4; gb.total = 256;
      MG(256, gb);
    }
  }

  flm_rms<<<1024, 256, 0, stream>>>(h, ln_out_w, nullptr, hn, nullptr);
  // head: 250 col-tiles x 8 row-tiles = 2000 blocks
  {
    GBatch gb;
    gb.d[0] = mkd(hn, 1024, bw ? (const float*)wemb : embed, 1024, out, nullptr, 32000,
                  0, 1024, 0, 0);
    gb.d[1] = gb.d[0]; gb.d[1].blk0 = 0x7fffffff;
    gb.d[2] = gb.d[1]; gb.d[3] = gb.d[1]; gb.d[4] = gb.d[1]; gb.d[5] = gb.d[1];
    gb.ng = 1; gb.total = 2000;
    MG(2000, gb);
  }
}